// Round 11
// baseline (228.363 us; speedup 1.0000x reference)
//
#include <hip/hip_runtime.h>

typedef unsigned int uint_t;
typedef unsigned short ushort_t;
typedef unsigned char uchar_t;
typedef _Float16 h2 __attribute__((ext_vector_type(2)));
typedef _Float16 f16x8 __attribute__((ext_vector_type(8)));
typedef float f32x4 __attribute__((ext_vector_type(4)));

#define NPTS 1024
#define DIM  128
#define NH2  64

__device__ __forceinline__ float dot2f(uint_t a, uint_t b, float c) {
#if __has_builtin(__builtin_amdgcn_fdot2)
    return __builtin_amdgcn_fdot2(__builtin_bit_cast(h2, a),
                                  __builtin_bit_cast(h2, b), c, false);
#else
    h2 ha = __builtin_bit_cast(h2, a);
    h2 hb = __builtin_bit_cast(h2, b);
    c += (float)ha[0] * (float)hb[0];
    c += (float)ha[1] * (float)hb[1];
    return c;
#endif
}

__device__ __forceinline__ uint_t umin_u(uint_t a, uint_t b) { return a < b ? a : b; }
__device__ __forceinline__ uint_t umax_u(uint_t a, uint_t b) { return a > b ? a : b; }
__device__ __forceinline__ uint_t pk_min_u16(uint_t a, uint_t b) {
    uint_t d; asm("v_pk_min_u16 %0, %1, %2" : "=v"(d) : "v"(a), "v"(b)); return d;
}
__device__ __forceinline__ uint_t pk_max_u16(uint_t a, uint_t b) {
    uint_t d; asm("v_pk_max_u16 %0, %1, %2" : "=v"(d) : "v"(a), "v"(b)); return d;
}
__device__ __forceinline__ uint_t pk_sub_u16w(uint_t a, uint_t b) {   // wrapping
    uint_t d; asm("v_pk_sub_u16 %0, %1, %2" : "=v"(d) : "v"(a), "v"(b)); return d;
}

#define DPP_UMIN(x, ctrl)                                                       \
    x = umin_u(x, (uint_t)__builtin_amdgcn_update_dpp((int)(x), (int)(x),       \
                                                      (ctrl), 0xf, 0xf, false))
#define DPP_REDUCE(x)                                                           \
    do { DPP_UMIN(x, 0x111); DPP_UMIN(x, 0x112); DPP_UMIN(x, 0x114);            \
         DPP_UMIN(x, 0x118); DPP_UMIN(x, 0x142); DPP_UMIN(x, 0x143); } while (0)

#define SEL_LO 0x05020400u
#define SEL_HI 0x07020600u

// async global->LDS, 16B per lane. LDS dest must be linear (wave-uniform base
// + lane*16); any swizzle is applied on the GLOBAL source address instead.
__device__ __forceinline__ void gload16(const void* g, void* l) {
#if __has_builtin(__builtin_amdgcn_global_load_lds)
    __builtin_amdgcn_global_load_lds(
        (__attribute__((address_space(1))) void*)(g),
        (__attribute__((address_space(3))) void*)(l), 16, 0, 0);
#else
    *(uint4*)l = *(const uint4*)g;
#endif
}

// ===================== K0a: prep — fp32 -> fp16 rows + norms ================
__global__ __launch_bounds__(256)
void prep_kernel(const float* __restrict__ reps, ushort_t* __restrict__ P16,
                 float* __restrict__ norms) {
    const int t   = threadIdx.x;
    const int row = blockIdx.x * 16 + (t >> 4);
    const int kx  = (t & 15) * 8;
    const float* src = reps + (size_t)row * DIM + kx;
    float4 v0 = *(const float4*)src;
    float4 v1 = *(const float4*)(src + 4);
    _Float16 h[8] = {(_Float16)v0.x, (_Float16)v0.y, (_Float16)v0.z, (_Float16)v0.w,
                     (_Float16)v1.x, (_Float16)v1.y, (_Float16)v1.z, (_Float16)v1.w};
    float nrm = 0.f;
    uint_t pk[4];
#pragma unroll
    for (int i = 0; i < 4; ++i) {
        float a = (float)h[2 * i], b = (float)h[2 * i + 1];
        nrm += a * a + b * b;
        pk[i] = (uint_t)__builtin_bit_cast(ushort_t, h[2 * i]) |
                ((uint_t)__builtin_bit_cast(ushort_t, h[2 * i + 1]) << 16);
    }
    *(uint4*)(P16 + (size_t)row * DIM + kx) = make_uint4(pk[0], pk[1], pk[2], pk[3]);
#pragma unroll
    for (int m = 1; m <= 8; m <<= 1) nrm += __shfl_xor(nrm, m, 16);
    if ((t & 15) == 0) norms[row] = nrm;
}

// ===================== K0b: norms only (tier 2) =============================
__global__ __launch_bounds__(256)
void norms_kernel(const float* __restrict__ reps, float* __restrict__ norms) {
    const int t   = threadIdx.x;
    const int row = blockIdx.x * 16 + (t >> 4);
    const int kx  = (t & 15) * 8;
    const float* src = reps + (size_t)row * DIM + kx;
    float4 v0 = *(const float4*)src;
    float4 v1 = *(const float4*)(src + 4);
    float nrm = 0.f;
    {
        _Float16 h[8] = {(_Float16)v0.x, (_Float16)v0.y, (_Float16)v0.z, (_Float16)v0.w,
                         (_Float16)v1.x, (_Float16)v1.y, (_Float16)v1.z, (_Float16)v1.w};
#pragma unroll
        for (int i = 0; i < 8; ++i) { float a = (float)h[i]; nrm += a * a; }
    }
#pragma unroll
    for (int m = 1; m <= 8; m <<= 1) nrm += __shfl_xor(nrm, m, 16);
    if ((t & 15) == 0) norms[row] = nrm;
}

// ===================== gram shared bits =====================================
__device__ __forceinline__ int swz(int row, int seg) {
    return (row << 7) + (((seg ^ row) & 15) << 3);
}
__device__ __forceinline__ uint_t packh2(float a, float b) {
    h2 p; p[0] = (_Float16)a; p[1] = (_Float16)b;
    return __builtin_bit_cast(uint_t, p);
}

__device__ __forceinline__ void gram_core_epilogue(
        f32x4 acc[2][8], const float* nrmS, uchar_t* Ds,
        int ti, int tj, int lane, int w) {
    const int cj = lane & 15;
    const int r4 = (lane >> 4) * 4;
    float na[2][4], nb[8];
#pragma unroll
    for (int mt = 0; mt < 2; ++mt)
#pragma unroll
        for (int r = 0; r < 4; ++r)
            na[mt][r] = nrmS[ti * 128 + w * 32 + mt * 16 + r4 + r];
#pragma unroll
    for (int nt = 0; nt < 8; ++nt) nb[nt] = nrmS[tj * 128 + nt * 16 + cj];
#pragma unroll
    for (int mt = 0; mt < 2; ++mt)
#pragma unroll
        for (int nt = 0; nt < 8; ++nt) {
            const int gj = tj * 128 + nt * 16 + cj;
#pragma unroll
            for (int r = 0; r < 4; ++r) {
                const int gi = ti * 128 + w * 32 + mt * 16 + r4 + r;
                float d2 = fmaxf(na[mt][r] + nb[nt] - 2.f * acc[mt][nt][r], 0.f);
                uint_t q = (uint_t)(d2 * 0.5f + 0.5f);
                q = q > 255u ? 255u : q;
                Ds[((size_t)gi << 10) + gj] = (uchar_t)q;
            }
        }
}

// stage one 64-point x 128-dim fp16 B-tile into LDS (linear dest,
// pre-swizzled source; involution: c&15 = sslot, source seg = (sslot^row)&15)
__device__ __forceinline__ void stageB64(const ushort_t* Ps, int tj,
                                         ushort_t* Bq, int t) {
#pragma unroll
    for (int i = 0; i < 4; ++i) {
        const int c   = t + i * 256;
        const int row = c >> 4;            // 0..63 (point within tile)
        const int seg = (c ^ row) & 15;
        gload16(Ps + (((size_t)(tj * 64 + row)) << 7) + (size_t)seg * 8,
                Bq + (size_t)c * 8);
    }
}

// ===================== K1a: row-strip Gram + fused NN4 (tier 1) =============
// R10 (resubmit; R10 bench was an infra timeout): restore TLP without L2
// thrash. R8's lesson: resident samples/XCD = (blk/CU x 32CU)/(blk/sample);
// panels must fit L2 (~2MB -> 8 samples). Decouple via blocks-per-sample:
// 64-row strips (16 blocks/sample, grid ns*16) with 64-point B-tiles (16KB,
// dbuf 32KB) + 4KB Ot = 36KB LDS -> 4 blk/CU (4 waves/SIMD, 2x R7's TLP)
// while resident samples/XCD stays 8 = 2MB. All arithmetic value-identical
// to R7 -> absmax 0. Decisive counter: FETCH_SIZE must stay ~21MB.
__global__ __launch_bounds__(256, 4)
void gram16f_kernel(const ushort_t* __restrict__ P16, const float* __restrict__ norms,
                    uchar_t* __restrict__ D8, uint_t* __restrict__ NN4,
                    int xcd_affine) {
    __shared__ ushort_t Bt[2][64 * 128];   // 2 x 16KB double buffer
    __shared__ uchar_t  Ot[64 * 64];       // 4KB out-tile staging
    const int bid = blockIdx.x;
    int s, ti;
    if (xcd_affine) {
        const int x = bid & 7, k = bid >> 3;   // sample s on XCD s%8
        s  = x + ((k >> 4) << 3);
        ti = k & 15;
    } else {
        s  = bid >> 4;
        ti = bid & 15;
    }
    const int t = threadIdx.x, lane = t & 63, w = t >> 6;

    const ushort_t* Ps = P16 + ((size_t)s * NPTS << 7);
    const ushort_t* Pa = Ps + ((size_t)ti * 64 << 7);
    const float*  nrmS = norms + (size_t)s * NPTS;
    uchar_t*      Ds   = D8 + ((size_t)s << 20);

    const int mrow = lane & 15;
    const int lg   = lane >> 4;
    const int cj   = lane & 15;
    const int r4   = (lane >> 4) * 4;
    const uint_t rr  = (uint_t)(lane & 3);
    const uint_t cl4 = (uint_t)(lane & 12);

    // strip row norms (fixed across tiles), bias prefolded. wave w owns
    // local rows w*16 .. w*16+15 of the 64-row strip.
    float ha[4];
#pragma unroll
    for (int r = 0; r < 4; ++r)
        ha[r] = 0.5f * nrmS[ti * 64 + w * 16 + r4 + r] + 0.5f;

    const ushort_t* parow0 = Pa + ((w * 16 + mrow) << 7);

    uint_t nnr[4] = {~0u, ~0u, ~0u, ~0u};

    const uint_t sel01 = rr | ((rr + 4u) << 8);

    stageB64(Ps, 0, &Bt[0][0], t);
    __syncthreads();

    for (int tj = 0; tj < 16; ++tj) {
        ushort_t* Bq = &Bt[tj & 1][0];
        if (tj < 15) stageB64(Ps, tj + 1, &Bt[(tj + 1) & 1][0], t);

        // ---- MFMA q-loop (A from global/L2, one step prefetched) ----
        f32x4 acc[4] = {};
        f16x8 a0 = *(const f16x8*)(parow0 + lg * 8);
#pragma unroll
        for (int q = 0; q < 4; ++q) {
            const int seg = q * 4 + lg;
            f16x8 a0c = a0;
            if (q < 3) a0 = *(const f16x8*)(parow0 + ((q + 1) * 4 + lg) * 8);
#pragma unroll
            for (int nt = 0; nt < 4; ++nt) {
                f16x8 b = *(const f16x8*)&Bq[swz(nt * 16 + mrow, seg)];
                acc[nt] = __builtin_amdgcn_mfma_f32_16x16x32_f16(a0c, b, acc[nt], 0, 0, 0);
            }
        }

        // ---- quantize + in-quad transpose (register only) ----
        float hb[4];
#pragma unroll
        for (int nt = 0; nt < 4; ++nt) hb[nt] = 0.5f * nrmS[tj * 64 + nt * 16 + cj];
        uint_t res[4];   // res[nt]: local row w*16+r4+rr, cols nt*16+cl4..+3
#pragma unroll
        for (int nt = 0; nt < 4; ++nt) {
            uint_t cp = 0;
#pragma unroll
            for (int r = 0; r < 4; ++r) {
                float f = (ha[r] + hb[nt]) - acc[nt][r];
#if __has_builtin(__builtin_amdgcn_cvt_pk_u8_f32)
                cp = __builtin_amdgcn_cvt_pk_u8_f32(f, (uint_t)r, cp);
#else
                uint_t qb = (uint_t)fminf(fmaxf(f, 0.f), 255.f);
                cp |= qb << (8 * r);
#endif
            }
            uint_t d0 = (uint_t)__builtin_amdgcn_update_dpp((int)cp, (int)cp, 0x00, 0xf, 0xf, false);
            uint_t d1 = (uint_t)__builtin_amdgcn_update_dpp((int)cp, (int)cp, 0x55, 0xf, 0xf, false);
            uint_t d2 = (uint_t)__builtin_amdgcn_update_dpp((int)cp, (int)cp, 0xaa, 0xf, 0xf, false);
            uint_t d3 = (uint_t)__builtin_amdgcn_update_dpp((int)cp, (int)cp, 0xff, 0xf, 0xf, false);
            uint_t lo  = __builtin_amdgcn_perm(d1, d0, sel01);
            uint_t hi  = __builtin_amdgcn_perm(d3, d2, sel01);
            res[nt] = __builtin_amdgcn_perm(hi, lo, 0x05040100u);
        }

        // ---- out-tile to LDS, coalesced flush to D8 ----
        __syncthreads();                    // prev flush reads done; staging drained
        const int lr  = w * 16 + r4 + (int)rr;   // local row 0..63
        const int c4b = lane & 12;
#pragma unroll
        for (int nt = 0; nt < 4; ++nt) {
            const int cs = nt ^ (lr & 3);   // swizzled 16B-chunk (4 chunks/row)
            *(uint_t*)&Ot[lr * 64 + cs * 16 + c4b] = res[nt];
        }
        __syncthreads();
        {
            const int r8 = lane >> 2, c = lane & 3;   // 16 rows x 4 chunks
            const int row = w * 16 + r8;
            const int cs  = c ^ (row & 3);
            uint4 vv = *(const uint4*)&Ot[row * 64 + cs * 16];
            *(uint4*)(Ds + (((size_t)(ti * 64 + row)) << 10) + tj * 64 + c * 16) = vv;
        }

        // ---- fused per-tile top-4 extraction (overlaps store drain) ----
        {
            uint_t md[8];   // u16 keys: (val<<8) | col_in_tile (col < 64)
#pragma unroll
            for (int nt = 0; nt < 4; ++nt) {
                const uint_t base = (uint_t)(nt * 16) + cl4;
                md[2 * nt]     = __builtin_amdgcn_perm(res[nt],
                                     ((base + 1u) << 16) | base, SEL_LO);
                md[2 * nt + 1] = __builtin_amdgcn_perm(res[nt],
                                     ((base + 3u) << 16) | (base + 2u), SEL_HI);
            }
            if (ti == tj) {   // poison self column (block-uniform branch)
                const uint_t cs = (uint_t)(w * 16 + r4) + rr;   // local row
#pragma unroll
                for (int m = 0; m < 8; ++m) {
                    const uint_t cb = (uint_t)((m >> 1) * 16) + cl4 + (uint_t)((m & 1) * 2);
                    uint_t h = (cs == cb) ? 0x0000FFFFu
                             : (cs == cb + 1u) ? 0xFFFF0000u : 0u;
                    md[m] |= h;
                }
            }
            uint_t prev = 0;   // threshold: round r excludes keys < prev via wrap-sub
#pragma unroll
            for (int r = 0; r < 4; ++r) {
                uint_t tm[8];
                if (r == 0) {
#pragma unroll
                    for (int m = 0; m < 8; ++m) tm[m] = md[m];
                } else {
                    const uint_t dd = prev | (prev << 16);
#pragma unroll
                    for (int m = 0; m < 8; ++m) tm[m] = pk_sub_u16w(md[m], dd);
                }
                uint_t t0 = pk_min_u16(pk_min_u16(tm[0], tm[1]), pk_min_u16(tm[2], tm[3]));
                uint_t t1 = pk_min_u16(pk_min_u16(tm[4], tm[5]), pk_min_u16(tm[6], tm[7]));
                uint_t T = pk_min_u16(t0, t1);
                // butterfly across the 4 lanes (lane^4, lane^8) holding this row
                T = pk_min_u16(T, (uint_t)__builtin_amdgcn_ds_swizzle((int)T, 0x101F));
                T = pk_min_u16(T, (uint_t)__builtin_amdgcn_ds_swizzle((int)T, 0x201F));
                const uint_t v = umin_u(T & 0xFFFFu, T >> 16) + prev;   // actual key
                prev = v + 1u;
                const uint_t g32 = ((v & 0xFF00u) << 2) | ((uint_t)tj << 6) | (v & 0x3Fu);
                // sorted insert into running top-4
                uint_t x = g32, mm;
                mm = umin_u(nnr[0], x); x = umax_u(nnr[0], x); nnr[0] = mm;
                mm = umin_u(nnr[1], x); x = umax_u(nnr[1], x); nnr[1] = mm;
                mm = umin_u(nnr[2], x); x = umax_u(nnr[2], x); nnr[2] = mm;
                nnr[3] = umin_u(nnr[3], x);
            }
        }
    }

    // ---- write NN4 (old nn4 format: 4 x u32 (q<<10|col) per row) ----
    if ((lane & 12) == 0) {
        const int grow = ti * 64 + w * 16 + r4 + (int)rr;
        *(uint4*)(NN4 + ((size_t)s * NPTS + (size_t)grow) * 4) =
            make_uint4(nnr[0], nnr[1], nnr[2], nnr[3]);
    }
}

// ===================== K1b: Gram from fp32 reps (tier 2) ====================
__global__ __launch_bounds__(256, 2)
void gram_kernel(const float* __restrict__ reps, const float* __restrict__ norms,
                 uchar_t* __restrict__ D8, int s_base) {
    __shared__ ushort_t At[128 * 128];
    __shared__ ushort_t Bt[128 * 128];
    const int bid  = blockIdx.x;
    const int sl   = bid >> 6, tile = bid & 63, ti = tile >> 3, tj = tile & 7;
    const int s    = s_base + sl;
    const int t    = threadIdx.x, lane = t & 63, w = t >> 6;

    const float* Pa = reps + ((size_t)s * NPTS + (size_t)ti * 128) * DIM;
    const float* Pb = reps + ((size_t)s * NPTS + (size_t)tj * 128) * DIM;
#pragma unroll
    for (int i = 0; i < 8; ++i) {
        int c = t + i * 256, row = c >> 4, seg = c & 15;
        const float* pa = Pa + row * DIM + seg * 8;
        const float* pb = Pb + row * DIM + seg * 8;
        float4 a0 = *(const float4*)pa, a1 = *(const float4*)(pa + 4);
        float4 b0 = *(const float4*)pb, b1 = *(const float4*)(pb + 4);
        *(uint4*)&At[swz(row, seg)] = make_uint4(packh2(a0.x, a0.y), packh2(a0.z, a0.w),
                                                 packh2(a1.x, a1.y), packh2(a1.z, a1.w));
        *(uint4*)&Bt[swz(row, seg)] = make_uint4(packh2(b0.x, b0.y), packh2(b0.z, b0.w),
                                                 packh2(b1.x, b1.y), packh2(b1.z, b1.w));
    }
    __syncthreads();

    f32x4 acc[2][8] = {};
    const int mrow = lane & 15;
    const int lg   = lane >> 4;
#pragma unroll
    for (int q = 0; q < 4; ++q) {
        const int seg = q * 4 + lg;
        f16x8 a0 = *(const f16x8*)&At[swz(w * 32 + mrow, seg)];
        f16x8 a1 = *(const f16x8*)&At[swz(w * 32 + 16 + mrow, seg)];
#pragma unroll
        for (int nt = 0; nt < 8; ++nt) {
            f16x8 b = *(const f16x8*)&Bt[swz(nt * 16 + mrow, seg)];
            acc[0][nt] = __builtin_amdgcn_mfma_f32_16x16x32_f16(a0, b, acc[0][nt], 0, 0, 0);
            acc[1][nt] = __builtin_amdgcn_mfma_f32_16x16x32_f16(a1, b, acc[1][nt], 0, 0, 0);
        }
    }
    gram_core_epilogue(acc, norms + (size_t)s * NPTS, D8 + ((size_t)sl << 20),
                       ti, tj, lane, w);
}

// ===================== K2: Borůvka v4 — approximate component min ===========
// unchanged (reads NN4 in the same format gram16f writes)
__global__ __launch_bounds__(1024)
void boruvka4_kernel(const uchar_t* __restrict__ D8, const uint_t* __restrict__ NN4,
                     float* __restrict__ out, float scale) {
    const int sl   = blockIdx.x;
    const int v    = threadIdx.x;
    const int lane = v & 63;
    const int wv   = v >> 6;
    const uchar_t* Dbase = D8 + ((size_t)sl << 20);

    __shared__ ushort_t root16[NPTS];
    __shared__ uint_t   best[NPTS];
    __shared__ ushort_t rq[64];
    __shared__ uint_t   rqn, ncomp_s;
    __shared__ float    fsum[16];

    uint4 nA = *(const uint4*)(NN4 + (((size_t)sl << 10) + (size_t)v) * 4);
    uint_t nn[4] = {nA.x, nA.y, nA.z, nA.w};

    root16[v] = (ushort_t)v;
    float acc = 0.f;
    __syncthreads();

    for (int round = 0; round < 48; ++round) {
        best[v] = 0xFFFFFFFFu;
        if (v == 0) { rqn = 0; ncomp_s = 0; }
        __syncthreads();   // A

        const uint_t rv = root16[v];

        uint_t cand = 0xFFFFFFFFu;
#pragma unroll
        for (int k = 0; k < 4; ++k) {
            uint_t e = nn[k];
            uint_t j = e & 1023u;
            if (root16[j] != (ushort_t)rv) {
                uint_t q = e >> 10;
                uint_t a = umin_u((uint_t)v, j), b = umax_u((uint_t)v, j);
                cand = umin_u(cand, (q << 20) | (a << 10) | b);
            }
        }
        if (cand != 0xFFFFFFFFu) atomicMin(&best[rv], cand);
        __syncthreads();   // B

        if (rv == (uint_t)v && best[v] == 0xFFFFFFFFu) {
            uint_t idx = atomicAdd(&rqn, 1u);
            if (idx < 64u) rq[idx] = (ushort_t)v;
        }
        __syncthreads();   // C

        if (rqn != 0u) {
            const uint_t nq = umin_u(rqn, 64u);
            for (uint_t qi = (uint_t)wv; qi < nq; qi += 16) {
                const uint_t row = rq[qi];
                const uint_t rr  = root16[row];
                uint4 r = ((const uint4*)(Dbase + ((size_t)row << 10)))[lane];
                uint_t bl = 0xFFFFFFFFu;
                const uint_t base = (uint_t)lane * 16u;
#pragma unroll
                for (int k = 0; k < 16; ++k) {
                    uint_t j = base + (uint_t)k;
                    uint_t q = (k < 4  ? (r.x >> (8 * k))
                              : k < 8  ? (r.y >> (8 * (k - 4)))
                              : k < 12 ? (r.z >> (8 * (k - 8)))
                                       : (r.w >> (8 * (k - 12)))) & 0xFFu;
                    uint_t a = umin_u(row, j), b = umax_u(row, j);
                    if (root16[j] != (ushort_t)rr)
                        bl = umin_u(bl, (q << 20) | (a << 10) | b);
                }
                DPP_REDUCE(bl);
                uint_t g = (uint_t)__builtin_amdgcn_readlane((int)bl, 63);
                if (lane == 0 && g != 0xFFFFFFFFu) atomicMin(&best[rr], g);
            }
            __syncthreads();   // D
        }

        bool hook = false;
        uint_t o = (uint_t)v;
        if (rv == (uint_t)v) {
            uint_t K = best[v];
            if (K != 0xFFFFFFFFu) {
                uint_t a = (K >> 10) & 1023u, b = K & 1023u, q = K >> 20;
                uint_t ra = root16[a], rb = root16[b];
                o = (ra == (uint_t)v) ? rb : ra;
                if (o < (uint_t)v) {
                    hook = true;
                    acc += sqrtf(2.0f * (float)q);
                }
            }
        }
        __syncthreads();   // E
        if (hook) root16[v] = (ushort_t)o;
        __syncthreads();   // F

        uint_t r = root16[v];
        uint_t pr = root16[r];
        for (int sg = 0; sg < 64 && pr != r; ++sg) { r = pr; pr = root16[r]; }
        __syncthreads();   // G
        root16[v] = (ushort_t)r;

        unsigned long long ball = __ballot(r == (uint_t)v);
        if (lane == 0) atomicAdd(&ncomp_s, (uint_t)__popcll(ball));
        __syncthreads();   // H
        if (ncomp_s == 1u) break;
    }

#pragma unroll
    for (int m = 32; m >= 1; m >>= 1) acc += __shfl_xor(acc, m, 64);
    if (lane == 0) fsum[wv] = acc;
    __syncthreads();
    if (v == 0) {
        float s = 0.f;
#pragma unroll
        for (int i = 0; i < 16; ++i) s += fsum[i];
        atomicAdd(out, s * scale);
    }
}

// ===================== tier 2: R9 Borůvka (proven @498µs) ===================
__global__ __launch_bounds__(1024)
void boruvka_kernel(const uchar_t* __restrict__ D8, float* __restrict__ out,
                    float scale) {
    const int sl   = blockIdx.x;
    const int v    = threadIdx.x;
    const int lane = v & 63;
    const int wv   = v >> 6;
    const uchar_t* Dbase = D8 + ((size_t)sl << 20);

    __shared__ uint_t   nnlist[NPTS * 8];
    __shared__ ushort_t root16[NPTS];
    __shared__ uint_t   best[NPTS];
    __shared__ ushort_t rq[NPTS];
    __shared__ uint_t   rqn, ncomp_s;
    __shared__ float    fsum[16];

    uint_t slotv[8];
#pragma unroll
    for (int m = 0; m < 8; ++m)
        slotv[m] = ((uint_t)(2 * m + 1) << 16) | (uint_t)(2 * m);

    {
        uint4 rc = ((const uint4*)(Dbase + ((size_t)wv << 10)))[lane];
        for (int i = 0; i < 64; ++i) {
            const int row = wv + 16 * i;
            uint4 rn = rc;
            if (i < 63)
                rn = ((const uint4*)(Dbase + ((size_t)(row + 16) << 10)))[lane];
            uint_t md[8];
            md[0] = __builtin_amdgcn_perm(rc.x, slotv[0], SEL_LO);
            md[1] = __builtin_amdgcn_perm(rc.x, slotv[1], SEL_HI);
            md[2] = __builtin_amdgcn_perm(rc.y, slotv[2], SEL_LO);
            md[3] = __builtin_amdgcn_perm(rc.y, slotv[3], SEL_HI);
            md[4] = __builtin_amdgcn_perm(rc.z, slotv[4], SEL_LO);
            md[5] = __builtin_amdgcn_perm(rc.z, slotv[5], SEL_HI);
            md[6] = __builtin_amdgcn_perm(rc.w, slotv[6], SEL_LO);
            md[7] = __builtin_amdgcn_perm(rc.w, slotv[7], SEL_HI);
            {
                const bool win = (row >> 4) == lane;
                const uint_t s4 = (uint_t)(row & 15);
#pragma unroll
                for (int m = 0; m < 8; ++m) {
                    uint_t h = (win && s4 == 2u * m)      ? 0x0000FFFFu
                             : (win && s4 == 2u * m + 1u) ? 0xFFFF0000u : 0u;
                    md[m] |= h;
                }
            }
#pragma unroll
            for (int k = 0; k < 8; ++k) {
                uint_t t0 = pk_min_u16(pk_min_u16(md[0], md[1]), pk_min_u16(md[2], md[3]));
                uint_t t1 = pk_min_u16(pk_min_u16(md[4], md[5]), pk_min_u16(md[6], md[7]));
                uint_t tt = pk_min_u16(t0, t1);
                uint_t v16 = umin_u(tt & 0xFFFFu, tt >> 16);
                uint_t key = ((v16 & 0xFF00u) << 2) | ((uint_t)lane << 4) | (v16 & 15u);
                DPP_REDUCE(key);
                uint_t g = (uint_t)__builtin_amdgcn_readlane((int)key, 63);
                if (lane == 0) nnlist[row * 8 + k] = g;
                const uint_t wl = (g >> 4) & 63u, ws = g & 15u;
                const bool win = (uint_t)lane == wl;
#pragma unroll
                for (int m = 0; m < 8; ++m) {
                    uint_t h = (win && ws == 2u * m)      ? 0x0000FFFFu
                             : (win && ws == 2u * m + 1u) ? 0xFFFF0000u : 0u;
                    md[m] |= h;
                }
            }
            rc = rn;
        }
    }
    root16[v] = (ushort_t)v;
    __syncthreads();

    uint_t nn[8];
#pragma unroll
    for (int k = 0; k < 8; ++k) nn[k] = nnlist[v * 8 + k];
    const uint_t q8 = nn[7] >> 10;

    float acc = 0.f;
    for (int round = 0; round < 12; ++round) {
        best[v] = 0xFFFFFFFFu;
        if (v == 0) { rqn = 0; ncomp_s = 0; }
        __syncthreads();
        const uint_t rv = root16[v];
        uint_t cand = 0xFFFFFFFFu;
#pragma unroll
        for (int k = 0; k < 8; ++k) {
            uint_t e = nn[k];
            uint_t j = e & 1023u;
            if (root16[j] != (ushort_t)rv) {
                uint_t q = e >> 10;
                uint_t a = umin_u((uint_t)v, j), b = umax_u((uint_t)v, j);
                cand = umin_u(cand, (q << 20) | (a << 10) | b);
            }
        }
        if (cand != 0xFFFFFFFFu) atomicMin(&best[rv], cand);
        if (cand == 0xFFFFFFFFu || (cand >> 20) >= q8) {
            uint_t idx = atomicAdd(&rqn, 1u);
            rq[idx] = (ushort_t)v;
        }
        __syncthreads();
        for (uint_t qi = (uint_t)wv; qi < rqn; qi += 16) {
            const uint_t row = rq[qi];
            const uint_t rr  = root16[row];
            uint4 r = ((const uint4*)(Dbase + ((size_t)row << 10)))[lane];
            uint_t bl = 0xFFFFFFFFu;
            const uint_t base = (uint_t)lane * 16u;
#pragma unroll
            for (int k = 0; k < 16; ++k) {
                uint_t j = base + (uint_t)k;
                uint_t q = (k < 4  ? (r.x >> (8 * k))
                          : k < 8  ? (r.y >> (8 * (k - 4)))
                          : k < 12 ? (r.z >> (8 * (k - 8)))
                                   : (r.w >> (8 * (k - 12)))) & 0xFFu;
                uint_t a = umin_u(row, j), b = umax_u(row, j);
                if (root16[j] != (ushort_t)rr)
                    bl = umin_u(bl, (q << 20) | (a << 10) | b);
            }
            DPP_REDUCE(bl);
            uint_t g = (uint_t)__builtin_amdgcn_readlane((int)bl, 63);
            if (lane == 0 && g != 0xFFFFFFFFu) atomicMin(&best[rr], g);
        }
        __syncthreads();
        const bool isroot = (rv == (uint_t)v);
        bool hook = false;
        uint_t o = (uint_t)v;
        if (isroot) {
            uint_t K = best[v];
            if (K != 0xFFFFFFFFu) {
                uint_t a = (K >> 10) & 1023u, b = K & 1023u, q = K >> 20;
                uint_t ra = root16[a], rb = root16[b];
                o = (ra == (uint_t)v) ? rb : ra;
                bool mutual = (best[o] == K);
                if (!mutual || (uint_t)v > o) {
                    hook = true;
                    acc += sqrtf(2.0f * (float)q);
                }
            }
        }
        __syncthreads();
        if (hook) root16[v] = (ushort_t)o;
        __syncthreads();
        uint_t r = root16[v];
        uint_t pr = root16[r];
        for (int sgs = 0; sgs < 1024 && pr != r; ++sgs) { r = pr; pr = root16[r]; }
        __syncthreads();
        root16[v] = (ushort_t)r;
        unsigned long long ball = __ballot(r == (uint_t)v);
        if (lane == 0) atomicAdd(&ncomp_s, (uint_t)__popcll(ball));
        __syncthreads();
        if (ncomp_s == 1u) break;
    }
#pragma unroll
    for (int m = 32; m >= 1; m >>= 1) acc += __shfl_xor(acc, m, 64);
    if (lane == 0) fsum[wv] = acc;
    __syncthreads();
    if (v == 0) {
        float s = 0.f;
#pragma unroll
        for (int i = 0; i < 16; ++i) s += fsum[i];
        atomicAdd(out, s * scale);
    }
}

// ===================== tier 3: single-wave Prim (R5) ========================
__global__ __launch_bounds__(64, 1)
void prim_u8_kernel(const uchar_t* __restrict__ D8, float* __restrict__ out,
                    float scale) {
    const int sl   = blockIdx.x;
    const int lane = threadIdx.x;
    const uchar_t* Dbase = D8 + ((size_t)sl << 20);

    uint_t md[8], po[8], slotv[8];
#pragma unroll
    for (int m = 0; m < 8; ++m) {
        md[m] = 0xFFFFFFFFu; po[m] = 0u;
        slotv[m] = ((uint_t)(2 * m + 1) << 16) | (uint_t)(2 * m);
    }
    const uint_t lane16 = (uint_t)lane << 4;
    uint_t p   = 0;
    float  acc = 0.f;

    for (int it = 0; it < NPTS - 1; ++it) {
        const uint4* rp = (const uint4*)(Dbase + ((size_t)p << 10));
        uint4 r = rp[lane];
        const bool  win = (p >> 4) == (uint_t)lane;
        const uint_t s4 = p & 15u;
#pragma unroll
        for (int m = 0; m < 8; ++m) {
            uint_t h = (win && s4 == 2u * m)      ? 0x0000FFFFu
                     : (win && s4 == 2u * m + 1u) ? 0xFFFF0000u : 0u;
            md[m] |= h; po[m] |= h;
        }
        md[0] = pk_min_u16(md[0], pk_max_u16(__builtin_amdgcn_perm(r.x, slotv[0], SEL_LO), po[0]));
        md[1] = pk_min_u16(md[1], pk_max_u16(__builtin_amdgcn_perm(r.x, slotv[1], SEL_HI), po[1]));
        md[2] = pk_min_u16(md[2], pk_max_u16(__builtin_amdgcn_perm(r.y, slotv[2], SEL_LO), po[2]));
        md[3] = pk_min_u16(md[3], pk_max_u16(__builtin_amdgcn_perm(r.y, slotv[3], SEL_HI), po[3]));
        md[4] = pk_min_u16(md[4], pk_max_u16(__builtin_amdgcn_perm(r.z, slotv[4], SEL_LO), po[4]));
        md[5] = pk_min_u16(md[5], pk_max_u16(__builtin_amdgcn_perm(r.z, slotv[5], SEL_HI), po[5]));
        md[6] = pk_min_u16(md[6], pk_max_u16(__builtin_amdgcn_perm(r.w, slotv[6], SEL_LO), po[6]));
        md[7] = pk_min_u16(md[7], pk_max_u16(__builtin_amdgcn_perm(r.w, slotv[7], SEL_HI), po[7]));

        uint_t t0 = pk_min_u16(pk_min_u16(md[0], md[1]), pk_min_u16(md[2], md[3]));
        uint_t t1 = pk_min_u16(pk_min_u16(md[4], md[5]), pk_min_u16(md[6], md[7]));
        uint_t tt = pk_min_u16(t0, t1);
        uint_t v16 = umin_u(tt & 0xFFFFu, tt >> 16);

        uint_t key = ((v16 & 0xFF00u) << 2) | lane16 | (v16 & 15u);
        DPP_REDUCE(key);
        uint_t g = (uint_t)__builtin_amdgcn_readlane((int)key, 63);

        p = g & 1023u;
        acc += sqrtf(2.0f * (float)(g >> 10));
    }
    if (lane == 0) atomicAdd(out, acc * scale);
}

// ===================== tier 4 fallback (R3) =================================
#define NTHR 256
#define NWAVE 4
#define PPT  4
__global__ __launch_bounds__(NTHR, 1)
void prim_mst_kernel(const float* __restrict__ reps, float* __restrict__ out,
                     float scale) {
    const int s = blockIdx.x, t = threadIdx.x, lane = t & 63, wave = t >> 6;
    __shared__ uint4  sc[NH2 / 4];
    __shared__ float  snrm;
    __shared__ __align__(16) uint_t warr[NWAVE];
    __shared__ float  facc[NWAVE];
    uint_t cx[PPT][NH2]; float nrm[PPT], mind[PPT];
#pragma unroll
    for (int p = 0; p < PPT; ++p) {
        const float4* src = (const float4*)(reps + (size_t)s * (NPTS * DIM) +
                                            (size_t)(p * NTHR + t) * DIM);
        float n = 0.f;
#pragma unroll
        for (int k = 0; k < 32; ++k) {
            float4 v = src[k];
            h2 a; a[0] = (_Float16)v.x; a[1] = (_Float16)v.y;
            h2 b; b[0] = (_Float16)v.z; b[1] = (_Float16)v.w;
            cx[p][2 * k] = __builtin_bit_cast(uint_t, a);
            cx[p][2 * k + 1] = __builtin_bit_cast(uint_t, b);
            n = dot2f(cx[p][2 * k], cx[p][2 * k], n);
            n = dot2f(cx[p][2 * k + 1], cx[p][2 * k + 1], n);
        }
        nrm[p] = n; mind[p] = 3.0e38f;
    }
    uint_t vis = 0;
    if (t == 0) {
#pragma unroll
        for (int k = 0; k < NH2 / 4; ++k)
            sc[k] = make_uint4(cx[0][4 * k], cx[0][4 * k + 1], cx[0][4 * k + 2], cx[0][4 * k + 3]);
        snrm = nrm[0]; vis = 1;
    }
    __syncthreads();
    float acc = 0.f;
    for (int it = 0; it < NPTS - 1; ++it) {
        const float bn = snrm;
        float e0[PPT], e1[PPT];
#pragma unroll
        for (int p = 0; p < PPT; ++p) { e0[p] = 0.f; e1[p] = 0.f; }
#pragma unroll
        for (int k = 0; k < NH2 / 4; ++k) {
            uint4 q = sc[k];
#pragma unroll
            for (int p = 0; p < PPT; ++p) {
                e0[p] = dot2f(cx[p][4 * k + 0], q.x, e0[p]);
                e1[p] = dot2f(cx[p][4 * k + 1], q.y, e1[p]);
                e0[p] = dot2f(cx[p][4 * k + 2], q.z, e0[p]);
                e1[p] = dot2f(cx[p][4 * k + 3], q.w, e1[p]);
            }
        }
        uint_t key = 0xFFFFFFFFu;
#pragma unroll
        for (int p = 0; p < PPT; ++p) {
            float d2 = fmaxf(bn + nrm[p] - 2.f * (e0[p] + e1[p]), 0.f);
            mind[p] = fminf(mind[p], d2);
            uint_t kp = ((vis >> p) & 1u) ? 0xFFFFFFFFu
                      : ((__float_as_uint(mind[p]) & 0xFFFFFC00u) | (uint_t)(p * NTHR + t));
            key = umin_u(key, kp);
        }
        DPP_REDUCE(key);
        uint_t wkey = (uint_t)__builtin_amdgcn_readlane((int)key, 63);
        if (lane == 0) warr[wave] = wkey;
        __syncthreads();
        uint4 wv = *(const uint4*)warr;
        uint_t g = umin_u(umin_u(wv.x, wv.y), umin_u(wv.z, wv.w));
        const int j = (int)(g & 0x3FFu), jp = j >> 8;
        if ((j & (NTHR - 1)) == t) {
#pragma unroll
            for (int p = 0; p < PPT; ++p)
                if (jp == p) {
#pragma unroll
                    for (int k = 0; k < NH2 / 4; ++k)
                        sc[k] = make_uint4(cx[p][4 * k], cx[p][4 * k + 1],
                                           cx[p][4 * k + 2], cx[p][4 * k + 3]);
                    snrm = nrm[p]; acc += sqrtf(mind[p]);
                }
            vis |= 1u << jp;
        }
        __syncthreads();
    }
#pragma unroll
    for (int m = 32; m >= 1; m >>= 1) acc += __shfl_xor(acc, m, 64);
    if (lane == 0) facc[wave] = acc;
    __syncthreads();
    if (t == 0) atomicAdd(out, (facc[0] + facc[1] + facc[2] + facc[3]) * scale);
}

// ============================ launch ========================================
extern "C" void kernel_launch(void* const* d_in, const int* in_sizes, int n_in,
                              void* d_out, int out_size, void* d_ws, size_t ws_size,
                              hipStream_t stream) {
    const float* reps = (const float*)d_in[0];
    float*       out  = (float*)d_out;
    const int ns = in_sizes[0] / (NPTS * DIM);
    const float scale = 1.0f / ((float)(NPTS - 1) * (float)ns * 2.0f);

    hipMemsetAsync(out, 0, sizeof(float), stream);

    const size_t bytes_D  = (size_t)ns << 20;
    const size_t bytes_P  = (size_t)ns << 18;
    const size_t bytes_NN = (size_t)ns << 14;   // 1024 rows * 4 * 4B
    const size_t bytes_N  = (size_t)ns << 12;

    if (ws_size >= bytes_D + bytes_P + bytes_NN + bytes_N) {
        // tier 1: prep -> 64-row-strip gram+NN4 fused -> Borůvka v4
        uchar_t*  D8    = (uchar_t*)d_ws;
        ushort_t* P16   = (ushort_t*)((char*)d_ws + bytes_D);
        uint_t*   NN4   = (uint_t*)((char*)d_ws + bytes_D + bytes_P);
        float*    norms = (float*)((char*)d_ws + bytes_D + bytes_P + bytes_NN);
        const int xcd_affine = ((ns & 7) == 0) ? 1 : 0;
        prep_kernel<<<dim3(ns * 64), dim3(256), 0, stream>>>(reps, P16, norms);
        gram16f_kernel<<<dim3(ns * 16), dim3(256), 0, stream>>>(P16, norms, D8, NN4,
                                                                xcd_affine);
        boruvka4_kernel<<<dim3(ns), dim3(1024), 0, stream>>>(D8, NN4, out, scale);
    } else if (ws_size >= bytes_D + bytes_N) {
        // tier 2: exact R9 path (proven 498 µs)
        uchar_t* D8    = (uchar_t*)d_ws;
        float*   norms = (float*)((char*)d_ws + bytes_D);
        norms_kernel<<<dim3(ns * 64), dim3(256), 0, stream>>>(reps, norms);
        gram_kernel<<<dim3(ns * 64), dim3(256), 0, stream>>>(reps, norms, D8, 0);
        boruvka_kernel<<<dim3(ns), dim3(1024), 0, stream>>>(D8, out, scale);
    } else {
        int nc = 0;
        size_t norms_off = 0;
        if (ws_size > bytes_N + (1u << 20)) {
            norms_off = (ws_size - bytes_N) & ~(size_t)15;
            nc = (int)(norms_off >> 20);
            if (nc > ns) nc = ns;
        }
        if (nc >= 32) {
            uchar_t* D8    = (uchar_t*)d_ws;
            float*   norms = (float*)((char*)d_ws + norms_off);
            norms_kernel<<<dim3(ns * 64), dim3(256), 0, stream>>>(reps, norms);
            for (int base = 0; base < ns; base += nc) {
                const int n = (ns - base < nc) ? (ns - base) : nc;
                gram_kernel<<<dim3(n * 64), dim3(256), 0, stream>>>(reps, norms, D8, base);
                prim_u8_kernel<<<dim3(n), dim3(64), 0, stream>>>(D8, out, scale);
            }
        } else {
            prim_mst_kernel<<<dim3(ns), dim3(NTHR), 0, stream>>>(reps, out, scale);
        }
    }
}

// Round 12
// 221.212 us; speedup vs baseline: 1.0323x; 1.0323x over previous
//
#include <hip/hip_runtime.h>

typedef unsigned int uint_t;
typedef unsigned short ushort_t;
typedef unsigned char uchar_t;
typedef _Float16 h2 __attribute__((ext_vector_type(2)));
typedef _Float16 f16x8 __attribute__((ext_vector_type(8)));
typedef float f32x4 __attribute__((ext_vector_type(4)));

#define NPTS 1024
#define DIM  128
#define NH2  64

__device__ __forceinline__ float dot2f(uint_t a, uint_t b, float c) {
#if __has_builtin(__builtin_amdgcn_fdot2)
    return __builtin_amdgcn_fdot2(__builtin_bit_cast(h2, a),
                                  __builtin_bit_cast(h2, b), c, false);
#else
    h2 ha = __builtin_bit_cast(h2, a);
    h2 hb = __builtin_bit_cast(h2, b);
    c += (float)ha[0] * (float)hb[0];
    c += (float)ha[1] * (float)hb[1];
    return c;
#endif
}

__device__ __forceinline__ uint_t umin_u(uint_t a, uint_t b) { return a < b ? a : b; }
__device__ __forceinline__ uint_t umax_u(uint_t a, uint_t b) { return a > b ? a : b; }
__device__ __forceinline__ uint_t pk_min_u16(uint_t a, uint_t b) {
    uint_t d; asm("v_pk_min_u16 %0, %1, %2" : "=v"(d) : "v"(a), "v"(b)); return d;
}
__device__ __forceinline__ uint_t pk_max_u16(uint_t a, uint_t b) {
    uint_t d; asm("v_pk_max_u16 %0, %1, %2" : "=v"(d) : "v"(a), "v"(b)); return d;
}
__device__ __forceinline__ uint_t pk_sub_u16w(uint_t a, uint_t b) {   // wrapping
    uint_t d; asm("v_pk_sub_u16 %0, %1, %2" : "=v"(d) : "v"(a), "v"(b)); return d;
}

#define DPP_UMIN(x, ctrl)                                                       \
    x = umin_u(x, (uint_t)__builtin_amdgcn_update_dpp((int)(x), (int)(x),       \
                                                      (ctrl), 0xf, 0xf, false))
#define DPP_REDUCE(x)                                                           \
    do { DPP_UMIN(x, 0x111); DPP_UMIN(x, 0x112); DPP_UMIN(x, 0x114);            \
         DPP_UMIN(x, 0x118); DPP_UMIN(x, 0x142); DPP_UMIN(x, 0x143); } while (0)

#define SEL_LO 0x05020400u
#define SEL_HI 0x07020600u

// async global->LDS, 16B per lane. LDS dest must be linear (wave-uniform base
// + lane*16); any swizzle is applied on the GLOBAL source address instead.
__device__ __forceinline__ void gload16(const void* g, void* l) {
#if __has_builtin(__builtin_amdgcn_global_load_lds)
    __builtin_amdgcn_global_load_lds(
        (__attribute__((address_space(1))) void*)(g),
        (__attribute__((address_space(3))) void*)(l), 16, 0, 0);
#else
    *(uint4*)l = *(const uint4*)g;
#endif
}

// ===================== K0a: prep — fp32 -> fp16 rows + norms ================
__global__ __launch_bounds__(256)
void prep_kernel(const float* __restrict__ reps, ushort_t* __restrict__ P16,
                 float* __restrict__ norms) {
    const int t   = threadIdx.x;
    const int row = blockIdx.x * 16 + (t >> 4);
    const int kx  = (t & 15) * 8;
    const float* src = reps + (size_t)row * DIM + kx;
    float4 v0 = *(const float4*)src;
    float4 v1 = *(const float4*)(src + 4);
    _Float16 h[8] = {(_Float16)v0.x, (_Float16)v0.y, (_Float16)v0.z, (_Float16)v0.w,
                     (_Float16)v1.x, (_Float16)v1.y, (_Float16)v1.z, (_Float16)v1.w};
    float nrm = 0.f;
    uint_t pk[4];
#pragma unroll
    for (int i = 0; i < 4; ++i) {
        float a = (float)h[2 * i], b = (float)h[2 * i + 1];
        nrm += a * a + b * b;
        pk[i] = (uint_t)__builtin_bit_cast(ushort_t, h[2 * i]) |
                ((uint_t)__builtin_bit_cast(ushort_t, h[2 * i + 1]) << 16);
    }
    *(uint4*)(P16 + (size_t)row * DIM + kx) = make_uint4(pk[0], pk[1], pk[2], pk[3]);
#pragma unroll
    for (int m = 1; m <= 8; m <<= 1) nrm += __shfl_xor(nrm, m, 16);
    if ((t & 15) == 0) norms[row] = nrm;
}

// ===================== K0b: norms only (tier 2) =============================
__global__ __launch_bounds__(256)
void norms_kernel(const float* __restrict__ reps, float* __restrict__ norms) {
    const int t   = threadIdx.x;
    const int row = blockIdx.x * 16 + (t >> 4);
    const int kx  = (t & 15) * 8;
    const float* src = reps + (size_t)row * DIM + kx;
    float4 v0 = *(const float4*)src;
    float4 v1 = *(const float4*)(src + 4);
    float nrm = 0.f;
    {
        _Float16 h[8] = {(_Float16)v0.x, (_Float16)v0.y, (_Float16)v0.z, (_Float16)v0.w,
                         (_Float16)v1.x, (_Float16)v1.y, (_Float16)v1.z, (_Float16)v1.w};
#pragma unroll
        for (int i = 0; i < 8; ++i) { float a = (float)h[i]; nrm += a * a; }
    }
#pragma unroll
    for (int m = 1; m <= 8; m <<= 1) nrm += __shfl_xor(nrm, m, 16);
    if ((t & 15) == 0) norms[row] = nrm;
}

// ===================== gram shared bits =====================================
__device__ __forceinline__ int swz(int row, int seg) {
    return (row << 7) + (((seg ^ row) & 15) << 3);
}
__device__ __forceinline__ uint_t packh2(float a, float b) {
    h2 p; p[0] = (_Float16)a; p[1] = (_Float16)b;
    return __builtin_bit_cast(uint_t, p);
}

__device__ __forceinline__ void gram_core_epilogue(
        f32x4 acc[2][8], const float* nrmS, uchar_t* Ds,
        int ti, int tj, int lane, int w) {
    const int cj = lane & 15;
    const int r4 = (lane >> 4) * 4;
    float na[2][4], nb[8];
#pragma unroll
    for (int mt = 0; mt < 2; ++mt)
#pragma unroll
        for (int r = 0; r < 4; ++r)
            na[mt][r] = nrmS[ti * 128 + w * 32 + mt * 16 + r4 + r];
#pragma unroll
    for (int nt = 0; nt < 8; ++nt) nb[nt] = nrmS[tj * 128 + nt * 16 + cj];
#pragma unroll
    for (int mt = 0; mt < 2; ++mt)
#pragma unroll
        for (int nt = 0; nt < 8; ++nt) {
            const int gj = tj * 128 + nt * 16 + cj;
#pragma unroll
            for (int r = 0; r < 4; ++r) {
                const int gi = ti * 128 + w * 32 + mt * 16 + r4 + r;
                float d2 = fmaxf(na[mt][r] + nb[nt] - 2.f * acc[mt][nt][r], 0.f);
                uint_t q = (uint_t)(d2 * 0.5f + 0.5f);
                q = q > 255u ? 255u : q;
                Ds[((size_t)gi << 10) + gj] = (uchar_t)q;
            }
        }
}

// stage one 64-point x 128-dim fp16 B-tile into LDS (linear dest,
// pre-swizzled source; involution: c&15 = sslot, source seg = (sslot^row)&15)
__device__ __forceinline__ void stageB64(const ushort_t* Ps, int tj,
                                         ushort_t* Bq, int t) {
#pragma unroll
    for (int i = 0; i < 4; ++i) {
        const int c   = t + i * 256;
        const int row = c >> 4;            // 0..63 (point within tile)
        const int seg = (c ^ row) & 15;
        gload16(Ps + (((size_t)(tj * 64 + row)) << 7) + (size_t)seg * 8,
                Bq + (size_t)c * 8);
    }
}

// ===================== K1a: row-strip Gram + fused NN4 (tier 1) =============
// R12: keep R10's occupancy geometry (64-row strips, 4 blk/CU, 8 resident
// samples/XCD = 2MB L2-fit — FETCH confirmed 21.7MB in R11), fix R11's two
// measured regressions: (1) SQ_LDS_BANK_CONFLICT 0->1.05M from the 64B-row
// Ot (16-bank row stride aliases rows); (2) WRITE_SIZE 133->185MB from 64B
// partial-line flushes. Fix: pair consecutive tj tiles into one Ot[64][128]
// (128B rows = R7's proven zero-conflict shape, XOR over 8 chunks), flush
// once per pair with full 128B rows. LDS 2x16KB Bt + 8KB Ot = 40KB.
// Byte-identical D8/NN4 -> absmax 0.
__global__ __launch_bounds__(256, 4)
void gram16f_kernel(const ushort_t* __restrict__ P16, const float* __restrict__ norms,
                    uchar_t* __restrict__ D8, uint_t* __restrict__ NN4,
                    int xcd_affine) {
    __shared__ ushort_t Bt[2][64 * 128];   // 2 x 16KB double buffer
    __shared__ uchar_t  Ot[64 * 128];      // 8KB pair out-tile (128B rows)
    const int bid = blockIdx.x;
    int s, ti;
    if (xcd_affine) {
        const int x = bid & 7, k = bid >> 3;   // sample s on XCD s%8
        s  = x + ((k >> 4) << 3);
        ti = k & 15;
    } else {
        s  = bid >> 4;
        ti = bid & 15;
    }
    const int t = threadIdx.x, lane = t & 63, w = t >> 6;

    const ushort_t* Ps = P16 + ((size_t)s * NPTS << 7);
    const ushort_t* Pa = Ps + ((size_t)ti * 64 << 7);
    const float*  nrmS = norms + (size_t)s * NPTS;
    uchar_t*      Ds   = D8 + ((size_t)s << 20);

    const int mrow = lane & 15;
    const int lg   = lane >> 4;
    const int cj   = lane & 15;
    const int r4   = (lane >> 4) * 4;
    const uint_t rr  = (uint_t)(lane & 3);
    const uint_t cl4 = (uint_t)(lane & 12);

    // strip row norms (fixed across tiles), bias prefolded. wave w owns
    // local rows w*16 .. w*16+15 of the 64-row strip.
    float ha[4];
#pragma unroll
    for (int r = 0; r < 4; ++r)
        ha[r] = 0.5f * nrmS[ti * 64 + w * 16 + r4 + r] + 0.5f;

    const ushort_t* parow0 = Pa + ((w * 16 + mrow) << 7);

    uint_t nnr[4] = {~0u, ~0u, ~0u, ~0u};

    const uint_t sel01 = rr | ((rr + 4u) << 8);

    stageB64(Ps, 0, &Bt[0][0], t);
    __syncthreads();

    for (int tj = 0; tj < 16; ++tj) {
        ushort_t* Bq = &Bt[tj & 1][0];
        if (tj < 15) stageB64(Ps, tj + 1, &Bt[(tj + 1) & 1][0], t);

        // ---- MFMA q-loop (A from global/L2, one step prefetched) ----
        f32x4 acc[4] = {};
        f16x8 a0 = *(const f16x8*)(parow0 + lg * 8);
#pragma unroll
        for (int q = 0; q < 4; ++q) {
            const int seg = q * 4 + lg;
            f16x8 a0c = a0;
            if (q < 3) a0 = *(const f16x8*)(parow0 + ((q + 1) * 4 + lg) * 8);
#pragma unroll
            for (int nt = 0; nt < 4; ++nt) {
                f16x8 b = *(const f16x8*)&Bq[swz(nt * 16 + mrow, seg)];
                acc[nt] = __builtin_amdgcn_mfma_f32_16x16x32_f16(a0c, b, acc[nt], 0, 0, 0);
            }
        }

        // ---- quantize + in-quad transpose (register only) ----
        float hb[4];
#pragma unroll
        for (int nt = 0; nt < 4; ++nt) hb[nt] = 0.5f * nrmS[tj * 64 + nt * 16 + cj];
        uint_t res[4];   // res[nt]: local row w*16+r4+rr, cols nt*16+cl4..+3
#pragma unroll
        for (int nt = 0; nt < 4; ++nt) {
            uint_t cp = 0;
#pragma unroll
            for (int r = 0; r < 4; ++r) {
                float f = (ha[r] + hb[nt]) - acc[nt][r];
#if __has_builtin(__builtin_amdgcn_cvt_pk_u8_f32)
                cp = __builtin_amdgcn_cvt_pk_u8_f32(f, (uint_t)r, cp);
#else
                uint_t qb = (uint_t)fminf(fmaxf(f, 0.f), 255.f);
                cp |= qb << (8 * r);
#endif
            }
            uint_t d0 = (uint_t)__builtin_amdgcn_update_dpp((int)cp, (int)cp, 0x00, 0xf, 0xf, false);
            uint_t d1 = (uint_t)__builtin_amdgcn_update_dpp((int)cp, (int)cp, 0x55, 0xf, 0xf, false);
            uint_t d2 = (uint_t)__builtin_amdgcn_update_dpp((int)cp, (int)cp, 0xaa, 0xf, 0xf, false);
            uint_t d3 = (uint_t)__builtin_amdgcn_update_dpp((int)cp, (int)cp, 0xff, 0xf, 0xf, false);
            uint_t lo  = __builtin_amdgcn_perm(d1, d0, sel01);
            uint_t hi  = __builtin_amdgcn_perm(d3, d2, sel01);
            res[nt] = __builtin_amdgcn_perm(hi, lo, 0x05040100u);
        }

        // ---- out-tile to LDS (pair-accumulated); flush every 2nd tile ----
        // slot chunk Y of row lr holds data chunk Y^(lr&7); tile tjp=tj&1
        // writes data chunks tjp*4+nt (cols (tjp*4+nt)*16 within the pair).
        __syncthreads();                    // prev pair-flush reads done; staging drained
        const int lr  = w * 16 + r4 + (int)rr;   // local row 0..63
        const int c4b = lane & 12;
        const int tjp = tj & 1;
#pragma unroll
        for (int nt = 0; nt < 4; ++nt) {
            const int cs = (tjp * 4 + nt) ^ (lr & 7);   // swizzled 16B chunk of 8
            *(uint_t*)&Ot[lr * 128 + cs * 16 + c4b] = res[nt];
        }
        if (tjp == 1) {
            __syncthreads();
            const int r8 = lane >> 3, c = lane & 7;   // 8 rows x 8 chunks = 128B/row
#pragma unroll
            for (int k = 0; k < 2; ++k) {
                const int row = w * 16 + k * 8 + r8;
                const int cs  = c ^ (row & 7);
                uint4 vv = *(const uint4*)&Ot[row * 128 + cs * 16];
                *(uint4*)(Ds + (((size_t)(ti * 64 + row)) << 10)
                             + (tj >> 1) * 128 + c * 16) = vv;
            }
        }

        // ---- fused per-tile top-4 extraction (overlaps store drain) ----
        {
            uint_t md[8];   // u16 keys: (val<<8) | col_in_tile (col < 64)
#pragma unroll
            for (int nt = 0; nt < 4; ++nt) {
                const uint_t base = (uint_t)(nt * 16) + cl4;
                md[2 * nt]     = __builtin_amdgcn_perm(res[nt],
                                     ((base + 1u) << 16) | base, SEL_LO);
                md[2 * nt + 1] = __builtin_amdgcn_perm(res[nt],
                                     ((base + 3u) << 16) | (base + 2u), SEL_HI);
            }
            if (ti == tj) {   // poison self column (block-uniform branch)
                const uint_t cs = (uint_t)(w * 16 + r4) + rr;   // local row
#pragma unroll
                for (int m = 0; m < 8; ++m) {
                    const uint_t cb = (uint_t)((m >> 1) * 16) + cl4 + (uint_t)((m & 1) * 2);
                    uint_t h = (cs == cb) ? 0x0000FFFFu
                             : (cs == cb + 1u) ? 0xFFFF0000u : 0u;
                    md[m] |= h;
                }
            }
            uint_t prev = 0;   // threshold: round r excludes keys < prev via wrap-sub
#pragma unroll
            for (int r = 0; r < 4; ++r) {
                uint_t tm[8];
                if (r == 0) {
#pragma unroll
                    for (int m = 0; m < 8; ++m) tm[m] = md[m];
                } else {
                    const uint_t dd = prev | (prev << 16);
#pragma unroll
                    for (int m = 0; m < 8; ++m) tm[m] = pk_sub_u16w(md[m], dd);
                }
                uint_t t0 = pk_min_u16(pk_min_u16(tm[0], tm[1]), pk_min_u16(tm[2], tm[3]));
                uint_t t1 = pk_min_u16(pk_min_u16(tm[4], tm[5]), pk_min_u16(tm[6], tm[7]));
                uint_t T = pk_min_u16(t0, t1);
                // butterfly across the 4 lanes (lane^4, lane^8) holding this row
                T = pk_min_u16(T, (uint_t)__builtin_amdgcn_ds_swizzle((int)T, 0x101F));
                T = pk_min_u16(T, (uint_t)__builtin_amdgcn_ds_swizzle((int)T, 0x201F));
                const uint_t v = umin_u(T & 0xFFFFu, T >> 16) + prev;   // actual key
                prev = v + 1u;
                const uint_t g32 = ((v & 0xFF00u) << 2) | ((uint_t)tj << 6) | (v & 0x3Fu);
                // sorted insert into running top-4
                uint_t x = g32, mm;
                mm = umin_u(nnr[0], x); x = umax_u(nnr[0], x); nnr[0] = mm;
                mm = umin_u(nnr[1], x); x = umax_u(nnr[1], x); nnr[1] = mm;
                mm = umin_u(nnr[2], x); x = umax_u(nnr[2], x); nnr[2] = mm;
                nnr[3] = umin_u(nnr[3], x);
            }
        }
    }

    // ---- write NN4 (old nn4 format: 4 x u32 (q<<10|col) per row) ----
    if ((lane & 12) == 0) {
        const int grow = ti * 64 + w * 16 + r4 + (int)rr;
        *(uint4*)(NN4 + ((size_t)s * NPTS + (size_t)grow) * 4) =
            make_uint4(nnr[0], nnr[1], nnr[2], nnr[3]);
    }
}

// ===================== K1b: Gram from fp32 reps (tier 2) ====================
__global__ __launch_bounds__(256, 2)
void gram_kernel(const float* __restrict__ reps, const float* __restrict__ norms,
                 uchar_t* __restrict__ D8, int s_base) {
    __shared__ ushort_t At[128 * 128];
    __shared__ ushort_t Bt[128 * 128];
    const int bid  = blockIdx.x;
    const int sl   = bid >> 6, tile = bid & 63, ti = tile >> 3, tj = tile & 7;
    const int s    = s_base + sl;
    const int t    = threadIdx.x, lane = t & 63, w = t >> 6;

    const float* Pa = reps + ((size_t)s * NPTS + (size_t)ti * 128) * DIM;
    const float* Pb = reps + ((size_t)s * NPTS + (size_t)tj * 128) * DIM;
#pragma unroll
    for (int i = 0; i < 8; ++i) {
        int c = t + i * 256, row = c >> 4, seg = c & 15;
        const float* pa = Pa + row * DIM + seg * 8;
        const float* pb = Pb + row * DIM + seg * 8;
        float4 a0 = *(const float4*)pa, a1 = *(const float4*)(pa + 4);
        float4 b0 = *(const float4*)pb, b1 = *(const float4*)(pb + 4);
        *(uint4*)&At[swz(row, seg)] = make_uint4(packh2(a0.x, a0.y), packh2(a0.z, a0.w),
                                                 packh2(a1.x, a1.y), packh2(a1.z, a1.w));
        *(uint4*)&Bt[swz(row, seg)] = make_uint4(packh2(b0.x, b0.y), packh2(b0.z, b0.w),
                                                 packh2(b1.x, b1.y), packh2(b1.z, b1.w));
    }
    __syncthreads();

    f32x4 acc[2][8] = {};
    const int mrow = lane & 15;
    const int lg   = lane >> 4;
#pragma unroll
    for (int q = 0; q < 4; ++q) {
        const int seg = q * 4 + lg;
        f16x8 a0 = *(const f16x8*)&At[swz(w * 32 + mrow, seg)];
        f16x8 a1 = *(const f16x8*)&At[swz(w * 32 + 16 + mrow, seg)];
#pragma unroll
        for (int nt = 0; nt < 8; ++nt) {
            f16x8 b = *(const f16x8*)&Bt[swz(nt * 16 + mrow, seg)];
            acc[0][nt] = __builtin_amdgcn_mfma_f32_16x16x32_f16(a0, b, acc[0][nt], 0, 0, 0);
            acc[1][nt] = __builtin_amdgcn_mfma_f32_16x16x32_f16(a1, b, acc[1][nt], 0, 0, 0);
        }
    }
    gram_core_epilogue(acc, norms + (size_t)s * NPTS, D8 + ((size_t)sl << 20),
                       ti, tj, lane, w);
}

// ===================== K2: Borůvka v4 — approximate component min ===========
// unchanged (reads NN4 in the same format gram16f writes)
__global__ __launch_bounds__(1024)
void boruvka4_kernel(const uchar_t* __restrict__ D8, const uint_t* __restrict__ NN4,
                     float* __restrict__ out, float scale) {
    const int sl   = blockIdx.x;
    const int v    = threadIdx.x;
    const int lane = v & 63;
    const int wv   = v >> 6;
    const uchar_t* Dbase = D8 + ((size_t)sl << 20);

    __shared__ ushort_t root16[NPTS];
    __shared__ uint_t   best[NPTS];
    __shared__ ushort_t rq[64];
    __shared__ uint_t   rqn, ncomp_s;
    __shared__ float    fsum[16];

    uint4 nA = *(const uint4*)(NN4 + (((size_t)sl << 10) + (size_t)v) * 4);
    uint_t nn[4] = {nA.x, nA.y, nA.z, nA.w};

    root16[v] = (ushort_t)v;
    float acc = 0.f;
    __syncthreads();

    for (int round = 0; round < 48; ++round) {
        best[v] = 0xFFFFFFFFu;
        if (v == 0) { rqn = 0; ncomp_s = 0; }
        __syncthreads();   // A

        const uint_t rv = root16[v];

        uint_t cand = 0xFFFFFFFFu;
#pragma unroll
        for (int k = 0; k < 4; ++k) {
            uint_t e = nn[k];
            uint_t j = e & 1023u;
            if (root16[j] != (ushort_t)rv) {
                uint_t q = e >> 10;
                uint_t a = umin_u((uint_t)v, j), b = umax_u((uint_t)v, j);
                cand = umin_u(cand, (q << 20) | (a << 10) | b);
            }
        }
        if (cand != 0xFFFFFFFFu) atomicMin(&best[rv], cand);
        __syncthreads();   // B

        if (rv == (uint_t)v && best[v] == 0xFFFFFFFFu) {
            uint_t idx = atomicAdd(&rqn, 1u);
            if (idx < 64u) rq[idx] = (ushort_t)v;
        }
        __syncthreads();   // C

        if (rqn != 0u) {
            const uint_t nq = umin_u(rqn, 64u);
            for (uint_t qi = (uint_t)wv; qi < nq; qi += 16) {
                const uint_t row = rq[qi];
                const uint_t rr  = root16[row];
                uint4 r = ((const uint4*)(Dbase + ((size_t)row << 10)))[lane];
                uint_t bl = 0xFFFFFFFFu;
                const uint_t base = (uint_t)lane * 16u;
#pragma unroll
                for (int k = 0; k < 16; ++k) {
                    uint_t j = base + (uint_t)k;
                    uint_t q = (k < 4  ? (r.x >> (8 * k))
                              : k < 8  ? (r.y >> (8 * (k - 4)))
                              : k < 12 ? (r.z >> (8 * (k - 8)))
                                       : (r.w >> (8 * (k - 12)))) & 0xFFu;
                    uint_t a = umin_u(row, j), b = umax_u(row, j);
                    if (root16[j] != (ushort_t)rr)
                        bl = umin_u(bl, (q << 20) | (a << 10) | b);
                }
                DPP_REDUCE(bl);
                uint_t g = (uint_t)__builtin_amdgcn_readlane((int)bl, 63);
                if (lane == 0 && g != 0xFFFFFFFFu) atomicMin(&best[rr], g);
            }
            __syncthreads();   // D
        }

        bool hook = false;
        uint_t o = (uint_t)v;
        if (rv == (uint_t)v) {
            uint_t K = best[v];
            if (K != 0xFFFFFFFFu) {
                uint_t a = (K >> 10) & 1023u, b = K & 1023u, q = K >> 20;
                uint_t ra = root16[a], rb = root16[b];
                o = (ra == (uint_t)v) ? rb : ra;
                if (o < (uint_t)v) {
                    hook = true;
                    acc += sqrtf(2.0f * (float)q);
                }
            }
        }
        __syncthreads();   // E
        if (hook) root16[v] = (ushort_t)o;
        __syncthreads();   // F

        uint_t r = root16[v];
        uint_t pr = root16[r];
        for (int sg = 0; sg < 64 && pr != r; ++sg) { r = pr; pr = root16[r]; }
        __syncthreads();   // G
        root16[v] = (ushort_t)r;

        unsigned long long ball = __ballot(r == (uint_t)v);
        if (lane == 0) atomicAdd(&ncomp_s, (uint_t)__popcll(ball));
        __syncthreads();   // H
        if (ncomp_s == 1u) break;
    }

#pragma unroll
    for (int m = 32; m >= 1; m >>= 1) acc += __shfl_xor(acc, m, 64);
    if (lane == 0) fsum[wv] = acc;
    __syncthreads();
    if (v == 0) {
        float s = 0.f;
#pragma unroll
        for (int i = 0; i < 16; ++i) s += fsum[i];
        atomicAdd(out, s * scale);
    }
}

// ===================== tier 2: R9 Borůvka (proven @498µs) ===================
__global__ __launch_bounds__(1024)
void boruvka_kernel(const uchar_t* __restrict__ D8, float* __restrict__ out,
                    float scale) {
    const int sl   = blockIdx.x;
    const int v    = threadIdx.x;
    const int lane = v & 63;
    const int wv   = v >> 6;
    const uchar_t* Dbase = D8 + ((size_t)sl << 20);

    __shared__ uint_t   nnlist[NPTS * 8];
    __shared__ ushort_t root16[NPTS];
    __shared__ uint_t   best[NPTS];
    __shared__ ushort_t rq[NPTS];
    __shared__ uint_t   rqn, ncomp_s;
    __shared__ float    fsum[16];

    uint_t slotv[8];
#pragma unroll
    for (int m = 0; m < 8; ++m)
        slotv[m] = ((uint_t)(2 * m + 1) << 16) | (uint_t)(2 * m);

    {
        uint4 rc = ((const uint4*)(Dbase + ((size_t)wv << 10)))[lane];
        for (int i = 0; i < 64; ++i) {
            const int row = wv + 16 * i;
            uint4 rn = rc;
            if (i < 63)
                rn = ((const uint4*)(Dbase + ((size_t)(row + 16) << 10)))[lane];
            uint_t md[8];
            md[0] = __builtin_amdgcn_perm(rc.x, slotv[0], SEL_LO);
            md[1] = __builtin_amdgcn_perm(rc.x, slotv[1], SEL_HI);
            md[2] = __builtin_amdgcn_perm(rc.y, slotv[2], SEL_LO);
            md[3] = __builtin_amdgcn_perm(rc.y, slotv[3], SEL_HI);
            md[4] = __builtin_amdgcn_perm(rc.z, slotv[4], SEL_LO);
            md[5] = __builtin_amdgcn_perm(rc.z, slotv[5], SEL_HI);
            md[6] = __builtin_amdgcn_perm(rc.w, slotv[6], SEL_LO);
            md[7] = __builtin_amdgcn_perm(rc.w, slotv[7], SEL_HI);
            {
                const bool win = (row >> 4) == lane;
                const uint_t s4 = (uint_t)(row & 15);
#pragma unroll
                for (int m = 0; m < 8; ++m) {
                    uint_t h = (win && s4 == 2u * m)      ? 0x0000FFFFu
                             : (win && s4 == 2u * m + 1u) ? 0xFFFF0000u : 0u;
                    md[m] |= h;
                }
            }
#pragma unroll
            for (int k = 0; k < 8; ++k) {
                uint_t t0 = pk_min_u16(pk_min_u16(md[0], md[1]), pk_min_u16(md[2], md[3]));
                uint_t t1 = pk_min_u16(pk_min_u16(md[4], md[5]), pk_min_u16(md[6], md[7]));
                uint_t tt = pk_min_u16(t0, t1);
                uint_t v16 = umin_u(tt & 0xFFFFu, tt >> 16);
                uint_t key = ((v16 & 0xFF00u) << 2) | ((uint_t)lane << 4) | (v16 & 15u);
                DPP_REDUCE(key);
                uint_t g = (uint_t)__builtin_amdgcn_readlane((int)key, 63);
                if (lane == 0) nnlist[row * 8 + k] = g;
                const uint_t wl = (g >> 4) & 63u, ws = g & 15u;
                const bool win = (uint_t)lane == wl;
#pragma unroll
                for (int m = 0; m < 8; ++m) {
                    uint_t h = (win && ws == 2u * m)      ? 0x0000FFFFu
                             : (win && ws == 2u * m + 1u) ? 0xFFFF0000u : 0u;
                    md[m] |= h;
                }
            }
            rc = rn;
        }
    }
    root16[v] = (ushort_t)v;
    __syncthreads();

    uint_t nn[8];
#pragma unroll
    for (int k = 0; k < 8; ++k) nn[k] = nnlist[v * 8 + k];
    const uint_t q8 = nn[7] >> 10;

    float acc = 0.f;
    for (int round = 0; round < 12; ++round) {
        best[v] = 0xFFFFFFFFu;
        if (v == 0) { rqn = 0; ncomp_s = 0; }
        __syncthreads();
        const uint_t rv = root16[v];
        uint_t cand = 0xFFFFFFFFu;
#pragma unroll
        for (int k = 0; k < 8; ++k) {
            uint_t e = nn[k];
            uint_t j = e & 1023u;
            if (root16[j] != (ushort_t)rv) {
                uint_t q = e >> 10;
                uint_t a = umin_u((uint_t)v, j), b = umax_u((uint_t)v, j);
                cand = umin_u(cand, (q << 20) | (a << 10) | b);
            }
        }
        if (cand != 0xFFFFFFFFu) atomicMin(&best[rv], cand);
        if (cand == 0xFFFFFFFFu || (cand >> 20) >= q8) {
            uint_t idx = atomicAdd(&rqn, 1u);
            rq[idx] = (ushort_t)v;
        }
        __syncthreads();
        for (uint_t qi = (uint_t)wv; qi < rqn; qi += 16) {
            const uint_t row = rq[qi];
            const uint_t rr  = root16[row];
            uint4 r = ((const uint4*)(Dbase + ((size_t)row << 10)))[lane];
            uint_t bl = 0xFFFFFFFFu;
            const uint_t base = (uint_t)lane * 16u;
#pragma unroll
            for (int k = 0; k < 16; ++k) {
                uint_t j = base + (uint_t)k;
                uint_t q = (k < 4  ? (r.x >> (8 * k))
                          : k < 8  ? (r.y >> (8 * (k - 4)))
                          : k < 12 ? (r.z >> (8 * (k - 8)))
                                   : (r.w >> (8 * (k - 12)))) & 0xFFu;
                uint_t a = umin_u(row, j), b = umax_u(row, j);
                if (root16[j] != (ushort_t)rr)
                    bl = umin_u(bl, (q << 20) | (a << 10) | b);
            }
            DPP_REDUCE(bl);
            uint_t g = (uint_t)__builtin_amdgcn_readlane((int)bl, 63);
            if (lane == 0 && g != 0xFFFFFFFFu) atomicMin(&best[rr], g);
        }
        __syncthreads();
        const bool isroot = (rv == (uint_t)v);
        bool hook = false;
        uint_t o = (uint_t)v;
        if (isroot) {
            uint_t K = best[v];
            if (K != 0xFFFFFFFFu) {
                uint_t a = (K >> 10) & 1023u, b = K & 1023u, q = K >> 20;
                uint_t ra = root16[a], rb = root16[b];
                o = (ra == (uint_t)v) ? rb : ra;
                bool mutual = (best[o] == K);
                if (!mutual || (uint_t)v > o) {
                    hook = true;
                    acc += sqrtf(2.0f * (float)q);
                }
            }
        }
        __syncthreads();
        if (hook) root16[v] = (ushort_t)o;
        __syncthreads();
        uint_t r = root16[v];
        uint_t pr = root16[r];
        for (int sgs = 0; sgs < 1024 && pr != r; ++sgs) { r = pr; pr = root16[r]; }
        __syncthreads();
        root16[v] = (ushort_t)r;
        unsigned long long ball = __ballot(r == (uint_t)v);
        if (lane == 0) atomicAdd(&ncomp_s, (uint_t)__popcll(ball));
        __syncthreads();
        if (ncomp_s == 1u) break;
    }
#pragma unroll
    for (int m = 32; m >= 1; m >>= 1) acc += __shfl_xor(acc, m, 64);
    if (lane == 0) fsum[wv] = acc;
    __syncthreads();
    if (v == 0) {
        float s = 0.f;
#pragma unroll
        for (int i = 0; i < 16; ++i) s += fsum[i];
        atomicAdd(out, s * scale);
    }
}

// ===================== tier 3: single-wave Prim (R5) ========================
__global__ __launch_bounds__(64, 1)
void prim_u8_kernel(const uchar_t* __restrict__ D8, float* __restrict__ out,
                    float scale) {
    const int sl   = blockIdx.x;
    const int lane = threadIdx.x;
    const uchar_t* Dbase = D8 + ((size_t)sl << 20);

    uint_t md[8], po[8], slotv[8];
#pragma unroll
    for (int m = 0; m < 8; ++m) {
        md[m] = 0xFFFFFFFFu; po[m] = 0u;
        slotv[m] = ((uint_t)(2 * m + 1) << 16) | (uint_t)(2 * m);
    }
    const uint_t lane16 = (uint_t)lane << 4;
    uint_t p   = 0;
    float  acc = 0.f;

    for (int it = 0; it < NPTS - 1; ++it) {
        const uint4* rp = (const uint4*)(Dbase + ((size_t)p << 10));
        uint4 r = rp[lane];
        const bool  win = (p >> 4) == (uint_t)lane;
        const uint_t s4 = p & 15u;
#pragma unroll
        for (int m = 0; m < 8; ++m) {
            uint_t h = (win && s4 == 2u * m)      ? 0x0000FFFFu
                     : (win && s4 == 2u * m + 1u) ? 0xFFFF0000u : 0u;
            md[m] |= h; po[m] |= h;
        }
        md[0] = pk_min_u16(md[0], pk_max_u16(__builtin_amdgcn_perm(r.x, slotv[0], SEL_LO), po[0]));
        md[1] = pk_min_u16(md[1], pk_max_u16(__builtin_amdgcn_perm(r.x, slotv[1], SEL_HI), po[1]));
        md[2] = pk_min_u16(md[2], pk_max_u16(__builtin_amdgcn_perm(r.y, slotv[2], SEL_LO), po[2]));
        md[3] = pk_min_u16(md[3], pk_max_u16(__builtin_amdgcn_perm(r.y, slotv[3], SEL_HI), po[3]));
        md[4] = pk_min_u16(md[4], pk_max_u16(__builtin_amdgcn_perm(r.z, slotv[4], SEL_LO), po[4]));
        md[5] = pk_min_u16(md[5], pk_max_u16(__builtin_amdgcn_perm(r.z, slotv[5], SEL_HI), po[5]));
        md[6] = pk_min_u16(md[6], pk_max_u16(__builtin_amdgcn_perm(r.w, slotv[6], SEL_LO), po[6]));
        md[7] = pk_min_u16(md[7], pk_max_u16(__builtin_amdgcn_perm(r.w, slotv[7], SEL_HI), po[7]));

        uint_t t0 = pk_min_u16(pk_min_u16(md[0], md[1]), pk_min_u16(md[2], md[3]));
        uint_t t1 = pk_min_u16(pk_min_u16(md[4], md[5]), pk_min_u16(md[6], md[7]));
        uint_t tt = pk_min_u16(t0, t1);
        uint_t v16 = umin_u(tt & 0xFFFFu, tt >> 16);

        uint_t key = ((v16 & 0xFF00u) << 2) | lane16 | (v16 & 15u);
        DPP_REDUCE(key);
        uint_t g = (uint_t)__builtin_amdgcn_readlane((int)key, 63);

        p = g & 1023u;
        acc += sqrtf(2.0f * (float)(g >> 10));
    }
    if (lane == 0) atomicAdd(out, acc * scale);
}

// ===================== tier 4 fallback (R3) =================================
#define NTHR 256
#define NWAVE 4
#define PPT  4
__global__ __launch_bounds__(NTHR, 1)
void prim_mst_kernel(const float* __restrict__ reps, float* __restrict__ out,
                     float scale) {
    const int s = blockIdx.x, t = threadIdx.x, lane = t & 63, wave = t >> 6;
    __shared__ uint4  sc[NH2 / 4];
    __shared__ float  snrm;
    __shared__ __align__(16) uint_t warr[NWAVE];
    __shared__ float  facc[NWAVE];
    uint_t cx[PPT][NH2]; float nrm[PPT], mind[PPT];
#pragma unroll
    for (int p = 0; p < PPT; ++p) {
        const float4* src = (const float4*)(reps + (size_t)s * (NPTS * DIM) +
                                            (size_t)(p * NTHR + t) * DIM);
        float n = 0.f;
#pragma unroll
        for (int k = 0; k < 32; ++k) {
            float4 v = src[k];
            h2 a; a[0] = (_Float16)v.x; a[1] = (_Float16)v.y;
            h2 b; b[0] = (_Float16)v.z; b[1] = (_Float16)v.w;
            cx[p][2 * k] = __builtin_bit_cast(uint_t, a);
            cx[p][2 * k + 1] = __builtin_bit_cast(uint_t, b);
            n = dot2f(cx[p][2 * k], cx[p][2 * k], n);
            n = dot2f(cx[p][2 * k + 1], cx[p][2 * k + 1], n);
        }
        nrm[p] = n; mind[p] = 3.0e38f;
    }
    uint_t vis = 0;
    if (t == 0) {
#pragma unroll
        for (int k = 0; k < NH2 / 4; ++k)
            sc[k] = make_uint4(cx[0][4 * k], cx[0][4 * k + 1], cx[0][4 * k + 2], cx[0][4 * k + 3]);
        snrm = nrm[0]; vis = 1;
    }
    __syncthreads();
    float acc = 0.f;
    for (int it = 0; it < NPTS - 1; ++it) {
        const float bn = snrm;
        float e0[PPT], e1[PPT];
#pragma unroll
        for (int p = 0; p < PPT; ++p) { e0[p] = 0.f; e1[p] = 0.f; }
#pragma unroll
        for (int k = 0; k < NH2 / 4; ++k) {
            uint4 q = sc[k];
#pragma unroll
            for (int p = 0; p < PPT; ++p) {
                e0[p] = dot2f(cx[p][4 * k + 0], q.x, e0[p]);
                e1[p] = dot2f(cx[p][4 * k + 1], q.y, e1[p]);
                e0[p] = dot2f(cx[p][4 * k + 2], q.z, e0[p]);
                e1[p] = dot2f(cx[p][4 * k + 3], q.w, e1[p]);
            }
        }
        uint_t key = 0xFFFFFFFFu;
#pragma unroll
        for (int p = 0; p < PPT; ++p) {
            float d2 = fmaxf(bn + nrm[p] - 2.f * (e0[p] + e1[p]), 0.f);
            mind[p] = fminf(mind[p], d2);
            uint_t kp = ((vis >> p) & 1u) ? 0xFFFFFFFFu
                      : ((__float_as_uint(mind[p]) & 0xFFFFFC00u) | (uint_t)(p * NTHR + t));
            key = umin_u(key, kp);
        }
        DPP_REDUCE(key);
        uint_t wkey = (uint_t)__builtin_amdgcn_readlane((int)key, 63);
        if (lane == 0) warr[wave] = wkey;
        __syncthreads();
        uint4 wv = *(const uint4*)warr;
        uint_t g = umin_u(umin_u(wv.x, wv.y), umin_u(wv.z, wv.w));
        const int j = (int)(g & 0x3FFu), jp = j >> 8;
        if ((j & (NTHR - 1)) == t) {
#pragma unroll
            for (int p = 0; p < PPT; ++p)
                if (jp == p) {
#pragma unroll
                    for (int k = 0; k < NH2 / 4; ++k)
                        sc[k] = make_uint4(cx[p][4 * k], cx[p][4 * k + 1],
                                           cx[p][4 * k + 2], cx[p][4 * k + 3]);
                    snrm = nrm[p]; acc += sqrtf(mind[p]);
                }
            vis |= 1u << jp;
        }
        __syncthreads();
    }
#pragma unroll
    for (int m = 32; m >= 1; m >>= 1) acc += __shfl_xor(acc, m, 64);
    if (lane == 0) facc[wave] = acc;
    __syncthreads();
    if (t == 0) atomicAdd(out, (facc[0] + facc[1] + facc[2] + facc[3]) * scale);
}

// ============================ launch ========================================
extern "C" void kernel_launch(void* const* d_in, const int* in_sizes, int n_in,
                              void* d_out, int out_size, void* d_ws, size_t ws_size,
                              hipStream_t stream) {
    const float* reps = (const float*)d_in[0];
    float*       out  = (float*)d_out;
    const int ns = in_sizes[0] / (NPTS * DIM);
    const float scale = 1.0f / ((float)(NPTS - 1) * (float)ns * 2.0f);

    hipMemsetAsync(out, 0, sizeof(float), stream);

    const size_t bytes_D  = (size_t)ns << 20;
    const size_t bytes_P  = (size_t)ns << 18;
    const size_t bytes_NN = (size_t)ns << 14;   // 1024 rows * 4 * 4B
    const size_t bytes_N  = (size_t)ns << 12;

    if (ws_size >= bytes_D + bytes_P + bytes_NN + bytes_N) {
        // tier 1: prep -> 64-row-strip gram+NN4 fused -> Borůvka v4
        uchar_t*  D8    = (uchar_t*)d_ws;
        ushort_t* P16   = (ushort_t*)((char*)d_ws + bytes_D);
        uint_t*   NN4   = (uint_t*)((char*)d_ws + bytes_D + bytes_P);
        float*    norms = (float*)((char*)d_ws + bytes_D + bytes_P + bytes_NN);
        const int xcd_affine = ((ns & 7) == 0) ? 1 : 0;
        prep_kernel<<<dim3(ns * 64), dim3(256), 0, stream>>>(reps, P16, norms);
        gram16f_kernel<<<dim3(ns * 16), dim3(256), 0, stream>>>(P16, norms, D8, NN4,
                                                                xcd_affine);
        boruvka4_kernel<<<dim3(ns), dim3(1024), 0, stream>>>(D8, NN4, out, scale);
    } else if (ws_size >= bytes_D + bytes_N) {
        // tier 2: exact R9 path (proven 498 µs)
        uchar_t* D8    = (uchar_t*)d_ws;
        float*   norms = (float*)((char*)d_ws + bytes_D);
        norms_kernel<<<dim3(ns * 64), dim3(256), 0, stream>>>(reps, norms);
        gram_kernel<<<dim3(ns * 64), dim3(256), 0, stream>>>(reps, norms, D8, 0);
        boruvka_kernel<<<dim3(ns), dim3(1024), 0, stream>>>(D8, out, scale);
    } else {
        int nc = 0;
        size_t norms_off = 0;
        if (ws_size > bytes_N + (1u << 20)) {
            norms_off = (ws_size - bytes_N) & ~(size_t)15;
            nc = (int)(norms_off >> 20);
            if (nc > ns) nc = ns;
        }
        if (nc >= 32) {
            uchar_t* D8    = (uchar_t*)d_ws;
            float*   norms = (float*)((char*)d_ws + norms_off);
            norms_kernel<<<dim3(ns * 64), dim3(256), 0, stream>>>(reps, norms);
            for (int base = 0; base < ns; base += nc) {
                const int n = (ns - base < nc) ? (ns - base) : nc;
                gram_kernel<<<dim3(n * 64), dim3(256), 0, stream>>>(reps, norms, D8, base);
                prim_u8_kernel<<<dim3(n), dim3(64), 0, stream>>>(D8, out, scale);
            }
        } else {
            prim_mst_kernel<<<dim3(ns), dim3(NTHR), 0, stream>>>(reps, out, scale);
        }
    }
}

// Round 15
// 201.559 us; speedup vs baseline: 1.1330x; 1.0975x over previous
//
#include <hip/hip_runtime.h>

typedef unsigned int uint_t;
typedef unsigned short ushort_t;
typedef unsigned char uchar_t;
typedef _Float16 h2 __attribute__((ext_vector_type(2)));
typedef _Float16 f16x8 __attribute__((ext_vector_type(8)));
typedef float f32x4 __attribute__((ext_vector_type(4)));

#define NPTS 1024
#define DIM  128
#define NH2  64

__device__ __forceinline__ float dot2f(uint_t a, uint_t b, float c) {
#if __has_builtin(__builtin_amdgcn_fdot2)
    return __builtin_amdgcn_fdot2(__builtin_bit_cast(h2, a),
                                  __builtin_bit_cast(h2, b), c, false);
#else
    h2 ha = __builtin_bit_cast(h2, a);
    h2 hb = __builtin_bit_cast(h2, b);
    c += (float)ha[0] * (float)hb[0];
    c += (float)ha[1] * (float)hb[1];
    return c;
#endif
}

__device__ __forceinline__ uint_t umin_u(uint_t a, uint_t b) { return a < b ? a : b; }
__device__ __forceinline__ uint_t umax_u(uint_t a, uint_t b) { return a > b ? a : b; }
__device__ __forceinline__ uint_t pk_min_u16(uint_t a, uint_t b) {
    uint_t d; asm("v_pk_min_u16 %0, %1, %2" : "=v"(d) : "v"(a), "v"(b)); return d;
}
__device__ __forceinline__ uint_t pk_max_u16(uint_t a, uint_t b) {
    uint_t d; asm("v_pk_max_u16 %0, %1, %2" : "=v"(d) : "v"(a), "v"(b)); return d;
}
__device__ __forceinline__ uint_t pk_sub_u16w(uint_t a, uint_t b) {   // wrapping
    uint_t d; asm("v_pk_sub_u16 %0, %1, %2" : "=v"(d) : "v"(a), "v"(b)); return d;
}

#define DPP_UMIN(x, ctrl)                                                       \
    x = umin_u(x, (uint_t)__builtin_amdgcn_update_dpp((int)(x), (int)(x),       \
                                                      (ctrl), 0xf, 0xf, false))
#define DPP_REDUCE(x)                                                           \
    do { DPP_UMIN(x, 0x111); DPP_UMIN(x, 0x112); DPP_UMIN(x, 0x114);            \
         DPP_UMIN(x, 0x118); DPP_UMIN(x, 0x142); DPP_UMIN(x, 0x143); } while (0)

#define SEL_LO 0x05020400u
#define SEL_HI 0x07020600u

// async global->LDS, 16B per lane. LDS dest must be linear (wave-uniform base
// + lane*16); any swizzle is applied on the GLOBAL source address instead.
__device__ __forceinline__ void gload16(const void* g, void* l) {
#if __has_builtin(__builtin_amdgcn_global_load_lds)
    __builtin_amdgcn_global_load_lds(
        (__attribute__((address_space(1))) void*)(g),
        (__attribute__((address_space(3))) void*)(l), 16, 0, 0);
#else
    *(uint4*)l = *(const uint4*)g;
#endif
}

// ===================== K0a: prep — fp32 -> fp16 rows + norms ================
__global__ __launch_bounds__(256)
void prep_kernel(const float* __restrict__ reps, ushort_t* __restrict__ P16,
                 float* __restrict__ norms) {
    const int t   = threadIdx.x;
    const int row = blockIdx.x * 16 + (t >> 4);
    const int kx  = (t & 15) * 8;
    const float* src = reps + (size_t)row * DIM + kx;
    float4 v0 = *(const float4*)src;
    float4 v1 = *(const float4*)(src + 4);
    _Float16 h[8] = {(_Float16)v0.x, (_Float16)v0.y, (_Float16)v0.z, (_Float16)v0.w,
                     (_Float16)v1.x, (_Float16)v1.y, (_Float16)v1.z, (_Float16)v1.w};
    float nrm = 0.f;
    uint_t pk[4];
#pragma unroll
    for (int i = 0; i < 4; ++i) {
        float a = (float)h[2 * i], b = (float)h[2 * i + 1];
        nrm += a * a + b * b;
        pk[i] = (uint_t)__builtin_bit_cast(ushort_t, h[2 * i]) |
                ((uint_t)__builtin_bit_cast(ushort_t, h[2 * i + 1]) << 16);
    }
    *(uint4*)(P16 + (size_t)row * DIM + kx) = make_uint4(pk[0], pk[1], pk[2], pk[3]);
#pragma unroll
    for (int m = 1; m <= 8; m <<= 1) nrm += __shfl_xor(nrm, m, 16);
    if ((t & 15) == 0) norms[row] = nrm;
}

// ===================== K0b: norms only (tier 2) =============================
__global__ __launch_bounds__(256)
void norms_kernel(const float* __restrict__ reps, float* __restrict__ norms) {
    const int t   = threadIdx.x;
    const int row = blockIdx.x * 16 + (t >> 4);
    const int kx  = (t & 15) * 8;
    const float* src = reps + (size_t)row * DIM + kx;
    float4 v0 = *(const float4*)src;
    float4 v1 = *(const float4*)(src + 4);
    float nrm = 0.f;
    {
        _Float16 h[8] = {(_Float16)v0.x, (_Float16)v0.y, (_Float16)v0.z, (_Float16)v0.w,
                         (_Float16)v1.x, (_Float16)v1.y, (_Float16)v1.z, (_Float16)v1.w};
#pragma unroll
        for (int i = 0; i < 8; ++i) { float a = (float)h[i]; nrm += a * a; }
    }
#pragma unroll
    for (int m = 1; m <= 8; m <<= 1) nrm += __shfl_xor(nrm, m, 16);
    if ((t & 15) == 0) norms[row] = nrm;
}

// ===================== gram shared bits =====================================
__device__ __forceinline__ int swz(int row, int seg) {
    return (row << 7) + (((seg ^ row) & 15) << 3);
}
__device__ __forceinline__ uint_t packh2(float a, float b) {
    h2 p; p[0] = (_Float16)a; p[1] = (_Float16)b;
    return __builtin_bit_cast(uint_t, p);
}

__device__ __forceinline__ void gram_core_epilogue(
        f32x4 acc[2][8], const float* nrmS, uchar_t* Ds,
        int ti, int tj, int lane, int w) {
    const int cj = lane & 15;
    const int r4 = (lane >> 4) * 4;
    float na[2][4], nb[8];
#pragma unroll
    for (int mt = 0; mt < 2; ++mt)
#pragma unroll
        for (int r = 0; r < 4; ++r)
            na[mt][r] = nrmS[ti * 128 + w * 32 + mt * 16 + r4 + r];
#pragma unroll
    for (int nt = 0; nt < 8; ++nt) nb[nt] = nrmS[tj * 128 + nt * 16 + cj];
#pragma unroll
    for (int mt = 0; mt < 2; ++mt)
#pragma unroll
        for (int nt = 0; nt < 8; ++nt) {
            const int gj = tj * 128 + nt * 16 + cj;
#pragma unroll
            for (int r = 0; r < 4; ++r) {
                const int gi = ti * 128 + w * 32 + mt * 16 + r4 + r;
                float d2 = fmaxf(na[mt][r] + nb[nt] - 2.f * acc[mt][nt][r], 0.f);
                uint_t q = (uint_t)(d2 * 0.5f + 0.5f);
                q = q > 255u ? 255u : q;
                Ds[((size_t)gi << 10) + gj] = (uchar_t)q;
            }
        }
}

// stage one 64-point x 128-dim fp16 B-tile into LDS (linear dest,
// pre-swizzled source; involution: c&15 = sslot, source seg = (sslot^row)&15)
__device__ __forceinline__ void stageB64(const ushort_t* Ps, int tj,
                                         ushort_t* Bq, int t) {
#pragma unroll
    for (int i = 0; i < 4; ++i) {
        const int c   = t + i * 256;
        const int row = c >> 4;            // 0..63 (point within tile)
        const int seg = (c ^ row) & 15;
        gload16(Ps + (((size_t)(tj * 64 + row)) << 7) + (size_t)seg * 8,
                Bq + (size_t)c * 8);
    }
}

// ===================== K1a: row-strip Gram + fused NN4 (tier 1) =============
// R13 (3rd resubmit; R13/R14 benches were infra timeouts): R12 fixed
// conflicts (1.05M->0) and WRITE (185->133MB) with no time delta — issue/
// lockstep-bound. This round trims issued work, value-identical: (a)
// A-fragments hoisted to registers once per strip (-64 L2 loads +
// addressing per thread); (b) barrier before Ot writes conditional on
// tjp==0 (pair halves write DISJOINT chunk sets; WAR vs previous pair-flush
// only at tjp==0). Barriers/strip 24->16. Byte-identical D8/NN4 -> absmax 0.
__global__ __launch_bounds__(256, 4)
void gram16f_kernel(const ushort_t* __restrict__ P16, const float* __restrict__ norms,
                    uchar_t* __restrict__ D8, uint_t* __restrict__ NN4,
                    int xcd_affine) {
    __shared__ ushort_t Bt[2][64 * 128];   // 2 x 16KB double buffer
    __shared__ uchar_t  Ot[64 * 128];      // 8KB pair out-tile (128B rows)
    const int bid = blockIdx.x;
    int s, ti;
    if (xcd_affine) {
        const int x = bid & 7, k = bid >> 3;   // sample s on XCD s%8
        s  = x + ((k >> 4) << 3);
        ti = k & 15;
    } else {
        s  = bid >> 4;
        ti = bid & 15;
    }
    const int t = threadIdx.x, lane = t & 63, w = t >> 6;

    const ushort_t* Ps = P16 + ((size_t)s * NPTS << 7);
    const ushort_t* Pa = Ps + ((size_t)ti * 64 << 7);
    const float*  nrmS = norms + (size_t)s * NPTS;
    uchar_t*      Ds   = D8 + ((size_t)s << 20);

    const int mrow = lane & 15;
    const int lg   = lane >> 4;
    const int cj   = lane & 15;
    const int r4   = (lane >> 4) * 4;
    const uint_t rr  = (uint_t)(lane & 3);
    const uint_t cl4 = (uint_t)(lane & 12);

    // strip row norms (fixed across tiles), bias prefolded. wave w owns
    // local rows w*16 .. w*16+15 of the 64-row strip.
    float ha[4];
#pragma unroll
    for (int r = 0; r < 4; ++r)
        ha[r] = 0.5f * nrmS[ti * 64 + w * 16 + r4 + r] + 0.5f;

    // A fragments hoisted: identical for every tile, load once per strip.
    const ushort_t* parow0 = Pa + ((w * 16 + mrow) << 7);
    f16x8 aq[4];
#pragma unroll
    for (int q = 0; q < 4; ++q)
        aq[q] = *(const f16x8*)(parow0 + (q * 4 + lg) * 8);

    uint_t nnr[4] = {~0u, ~0u, ~0u, ~0u};

    const uint_t sel01 = rr | ((rr + 4u) << 8);

    stageB64(Ps, 0, &Bt[0][0], t);
    __syncthreads();

    for (int tj = 0; tj < 16; ++tj) {
        ushort_t* Bq = &Bt[tj & 1][0];
        if (tj < 15) stageB64(Ps, tj + 1, &Bt[(tj + 1) & 1][0], t);

        // ---- MFMA q-loop (A in registers) ----
        f32x4 acc[4] = {};
#pragma unroll
        for (int q = 0; q < 4; ++q) {
            const int seg = q * 4 + lg;
#pragma unroll
            for (int nt = 0; nt < 4; ++nt) {
                f16x8 b = *(const f16x8*)&Bq[swz(nt * 16 + mrow, seg)];
                acc[nt] = __builtin_amdgcn_mfma_f32_16x16x32_f16(aq[q], b, acc[nt], 0, 0, 0);
            }
        }

        // ---- quantize + in-quad transpose (register only) ----
        float hb[4];
#pragma unroll
        for (int nt = 0; nt < 4; ++nt) hb[nt] = 0.5f * nrmS[tj * 64 + nt * 16 + cj];
        uint_t res[4];   // res[nt]: local row w*16+r4+rr, cols nt*16+cl4..+3
#pragma unroll
        for (int nt = 0; nt < 4; ++nt) {
            uint_t cp = 0;
#pragma unroll
            for (int r = 0; r < 4; ++r) {
                float f = (ha[r] + hb[nt]) - acc[nt][r];
#if __has_builtin(__builtin_amdgcn_cvt_pk_u8_f32)
                cp = __builtin_amdgcn_cvt_pk_u8_f32(f, (uint_t)r, cp);
#else
                uint_t qb = (uint_t)fminf(fmaxf(f, 0.f), 255.f);
                cp |= qb << (8 * r);
#endif
            }
            uint_t d0 = (uint_t)__builtin_amdgcn_update_dpp((int)cp, (int)cp, 0x00, 0xf, 0xf, false);
            uint_t d1 = (uint_t)__builtin_amdgcn_update_dpp((int)cp, (int)cp, 0x55, 0xf, 0xf, false);
            uint_t d2 = (uint_t)__builtin_amdgcn_update_dpp((int)cp, (int)cp, 0xaa, 0xf, 0xf, false);
            uint_t d3 = (uint_t)__builtin_amdgcn_update_dpp((int)cp, (int)cp, 0xff, 0xf, 0xf, false);
            uint_t lo  = __builtin_amdgcn_perm(d1, d0, sel01);
            uint_t hi  = __builtin_amdgcn_perm(d3, d2, sel01);
            res[nt] = __builtin_amdgcn_perm(hi, lo, 0x05040100u);
        }

        // ---- out-tile to LDS (pair-accumulated); flush every 2nd tile ----
        // slot chunk Y of row lr holds data chunk Y^(lr&7); tile tjp=tj&1
        // writes data chunks tjp*4+nt. tjp0 and tjp1 write DISJOINT chunk
        // sets, so the WAR barrier vs the previous pair-flush is only needed
        // at tjp==0.
        const int lr  = w * 16 + r4 + (int)rr;   // local row 0..63
        const int c4b = lane & 12;
        const int tjp = tj & 1;
        if (tjp == 0) __syncthreads();      // prev pair-flush reads done
#pragma unroll
        for (int nt = 0; nt < 4; ++nt) {
            const int cs = (tjp * 4 + nt) ^ (lr & 7);   // swizzled 16B chunk of 8
            *(uint_t*)&Ot[lr * 128 + cs * 16 + c4b] = res[nt];
        }
        if (tjp == 1) {
            __syncthreads();
            const int r8 = lane >> 3, c = lane & 7;   // 8 rows x 8 chunks = 128B/row
#pragma unroll
            for (int k = 0; k < 2; ++k) {
                const int row = w * 16 + k * 8 + r8;
                const int cs  = c ^ (row & 7);
                uint4 vv = *(const uint4*)&Ot[row * 128 + cs * 16];
                *(uint4*)(Ds + (((size_t)(ti * 64 + row)) << 10)
                             + (tj >> 1) * 128 + c * 16) = vv;
            }
        }

        // ---- fused per-tile top-4 extraction (overlaps store drain) ----
        {
            uint_t md[8];   // u16 keys: (val<<8) | col_in_tile (col < 64)
#pragma unroll
            for (int nt = 0; nt < 4; ++nt) {
                const uint_t base = (uint_t)(nt * 16) + cl4;
                md[2 * nt]     = __builtin_amdgcn_perm(res[nt],
                                     ((base + 1u) << 16) | base, SEL_LO);
                md[2 * nt + 1] = __builtin_amdgcn_perm(res[nt],
                                     ((base + 3u) << 16) | (base + 2u), SEL_HI);
            }
            if (ti == tj) {   // poison self column (block-uniform branch)
                const uint_t cs = (uint_t)(w * 16 + r4) + rr;   // local row
#pragma unroll
                for (int m = 0; m < 8; ++m) {
                    const uint_t cb = (uint_t)((m >> 1) * 16) + cl4 + (uint_t)((m & 1) * 2);
                    uint_t h = (cs == cb) ? 0x0000FFFFu
                             : (cs == cb + 1u) ? 0xFFFF0000u : 0u;
                    md[m] |= h;
                }
            }
            uint_t prev = 0;   // threshold: round r excludes keys < prev via wrap-sub
#pragma unroll
            for (int r = 0; r < 4; ++r) {
                uint_t tm[8];
                if (r == 0) {
#pragma unroll
                    for (int m = 0; m < 8; ++m) tm[m] = md[m];
                } else {
                    const uint_t dd = prev | (prev << 16);
#pragma unroll
                    for (int m = 0; m < 8; ++m) tm[m] = pk_sub_u16w(md[m], dd);
                }
                uint_t t0 = pk_min_u16(pk_min_u16(tm[0], tm[1]), pk_min_u16(tm[2], tm[3]));
                uint_t t1 = pk_min_u16(pk_min_u16(tm[4], tm[5]), pk_min_u16(tm[6], tm[7]));
                uint_t T = pk_min_u16(t0, t1);
                // butterfly across the 4 lanes (lane^4, lane^8) holding this row
                T = pk_min_u16(T, (uint_t)__builtin_amdgcn_ds_swizzle((int)T, 0x101F));
                T = pk_min_u16(T, (uint_t)__builtin_amdgcn_ds_swizzle((int)T, 0x201F));
                const uint_t v = umin_u(T & 0xFFFFu, T >> 16) + prev;   // actual key
                prev = v + 1u;
                const uint_t g32 = ((v & 0xFF00u) << 2) | ((uint_t)tj << 6) | (v & 0x3Fu);
                // sorted insert into running top-4
                uint_t x = g32, mm;
                mm = umin_u(nnr[0], x); x = umax_u(nnr[0], x); nnr[0] = mm;
                mm = umin_u(nnr[1], x); x = umax_u(nnr[1], x); nnr[1] = mm;
                mm = umin_u(nnr[2], x); x = umax_u(nnr[2], x); nnr[2] = mm;
                nnr[3] = umin_u(nnr[3], x);
            }
        }
    }

    // ---- write NN4 (old nn4 format: 4 x u32 (q<<10|col) per row) ----
    if ((lane & 12) == 0) {
        const int grow = ti * 64 + w * 16 + r4 + (int)rr;
        *(uint4*)(NN4 + ((size_t)s * NPTS + (size_t)grow) * 4) =
            make_uint4(nnr[0], nnr[1], nnr[2], nnr[3]);
    }
}

// ===================== K1b: Gram from fp32 reps (tier 2) ====================
__global__ __launch_bounds__(256, 2)
void gram_kernel(const float* __restrict__ reps, const float* __restrict__ norms,
                 uchar_t* __restrict__ D8, int s_base) {
    __shared__ ushort_t At[128 * 128];
    __shared__ ushort_t Bt[128 * 128];
    const int bid  = blockIdx.x;
    const int sl   = bid >> 6, tile = bid & 63, ti = tile >> 3, tj = tile & 7;
    const int s    = s_base + sl;
    const int t    = threadIdx.x, lane = t & 63, w = t >> 6;

    const float* Pa = reps + ((size_t)s * NPTS + (size_t)ti * 128) * DIM;
    const float* Pb = reps + ((size_t)s * NPTS + (size_t)tj * 128) * DIM;
#pragma unroll
    for (int i = 0; i < 8; ++i) {
        int c = t + i * 256, row = c >> 4, seg = c & 15;
        const float* pa = Pa + row * DIM + seg * 8;
        const float* pb = Pb + row * DIM + seg * 8;
        float4 a0 = *(const float4*)pa, a1 = *(const float4*)(pa + 4);
        float4 b0 = *(const float4*)pb, b1 = *(const float4*)(pb + 4);
        *(uint4*)&At[swz(row, seg)] = make_uint4(packh2(a0.x, a0.y), packh2(a0.z, a0.w),
                                                 packh2(a1.x, a1.y), packh2(a1.z, a1.w));
        *(uint4*)&Bt[swz(row, seg)] = make_uint4(packh2(b0.x, b0.y), packh2(b0.z, b0.w),
                                                 packh2(b1.x, b1.y), packh2(b1.z, b1.w));
    }
    __syncthreads();

    f32x4 acc[2][8] = {};
    const int mrow = lane & 15;
    const int lg   = lane >> 4;
#pragma unroll
    for (int q = 0; q < 4; ++q) {
        const int seg = q * 4 + lg;
        f16x8 a0 = *(const f16x8*)&At[swz(w * 32 + mrow, seg)];
        f16x8 a1 = *(const f16x8*)&At[swz(w * 32 + 16 + mrow, seg)];
#pragma unroll
        for (int nt = 0; nt < 8; ++nt) {
            f16x8 b = *(const f16x8*)&Bt[swz(nt * 16 + mrow, seg)];
            acc[0][nt] = __builtin_amdgcn_mfma_f32_16x16x32_f16(a0, b, acc[0][nt], 0, 0, 0);
            acc[1][nt] = __builtin_amdgcn_mfma_f32_16x16x32_f16(a1, b, acc[1][nt], 0, 0, 0);
        }
    }
    gram_core_epilogue(acc, norms + (size_t)s * NPTS, D8 + ((size_t)sl << 20),
                       ti, tj, lane, w);
}

// ===================== K2: Borůvka v4 — approximate component min ===========
// unchanged (reads NN4 in the same format gram16f writes)
__global__ __launch_bounds__(1024)
void boruvka4_kernel(const uchar_t* __restrict__ D8, const uint_t* __restrict__ NN4,
                     float* __restrict__ out, float scale) {
    const int sl   = blockIdx.x;
    const int v    = threadIdx.x;
    const int lane = v & 63;
    const int wv   = v >> 6;
    const uchar_t* Dbase = D8 + ((size_t)sl << 20);

    __shared__ ushort_t root16[NPTS];
    __shared__ uint_t   best[NPTS];
    __shared__ ushort_t rq[64];
    __shared__ uint_t   rqn, ncomp_s;
    __shared__ float    fsum[16];

    uint4 nA = *(const uint4*)(NN4 + (((size_t)sl << 10) + (size_t)v) * 4);
    uint_t nn[4] = {nA.x, nA.y, nA.z, nA.w};

    root16[v] = (ushort_t)v;
    float acc = 0.f;
    __syncthreads();

    for (int round = 0; round < 48; ++round) {
        best[v] = 0xFFFFFFFFu;
        if (v == 0) { rqn = 0; ncomp_s = 0; }
        __syncthreads();   // A

        const uint_t rv = root16[v];

        uint_t cand = 0xFFFFFFFFu;
#pragma unroll
        for (int k = 0; k < 4; ++k) {
            uint_t e = nn[k];
            uint_t j = e & 1023u;
            if (root16[j] != (ushort_t)rv) {
                uint_t q = e >> 10;
                uint_t a = umin_u((uint_t)v, j), b = umax_u((uint_t)v, j);
                cand = umin_u(cand, (q << 20) | (a << 10) | b);
            }
        }
        if (cand != 0xFFFFFFFFu) atomicMin(&best[rv], cand);
        __syncthreads();   // B

        if (rv == (uint_t)v && best[v] == 0xFFFFFFFFu) {
            uint_t idx = atomicAdd(&rqn, 1u);
            if (idx < 64u) rq[idx] = (ushort_t)v;
        }
        __syncthreads();   // C

        if (rqn != 0u) {
            const uint_t nq = umin_u(rqn, 64u);
            for (uint_t qi = (uint_t)wv; qi < nq; qi += 16) {
                const uint_t row = rq[qi];
                const uint_t rr  = root16[row];
                uint4 r = ((const uint4*)(Dbase + ((size_t)row << 10)))[lane];
                uint_t bl = 0xFFFFFFFFu;
                const uint_t base = (uint_t)lane * 16u;
#pragma unroll
                for (int k = 0; k < 16; ++k) {
                    uint_t j = base + (uint_t)k;
                    uint_t q = (k < 4  ? (r.x >> (8 * k))
                              : k < 8  ? (r.y >> (8 * (k - 4)))
                              : k < 12 ? (r.z >> (8 * (k - 8)))
                                       : (r.w >> (8 * (k - 12)))) & 0xFFu;
                    uint_t a = umin_u(row, j), b = umax_u(row, j);
                    if (root16[j] != (ushort_t)rr)
                        bl = umin_u(bl, (q << 20) | (a << 10) | b);
                }
                DPP_REDUCE(bl);
                uint_t g = (uint_t)__builtin_amdgcn_readlane((int)bl, 63);
                if (lane == 0 && g != 0xFFFFFFFFu) atomicMin(&best[rr], g);
            }
            __syncthreads();   // D
        }

        bool hook = false;
        uint_t o = (uint_t)v;
        if (rv == (uint_t)v) {
            uint_t K = best[v];
            if (K != 0xFFFFFFFFu) {
                uint_t a = (K >> 10) & 1023u, b = K & 1023u, q = K >> 20;
                uint_t ra = root16[a], rb = root16[b];
                o = (ra == (uint_t)v) ? rb : ra;
                if (o < (uint_t)v) {
                    hook = true;
                    acc += sqrtf(2.0f * (float)q);
                }
            }
        }
        __syncthreads();   // E
        if (hook) root16[v] = (ushort_t)o;
        __syncthreads();   // F

        uint_t r = root16[v];
        uint_t pr = root16[r];
        for (int sg = 0; sg < 64 && pr != r; ++sg) { r = pr; pr = root16[r]; }
        __syncthreads();   // G
        root16[v] = (ushort_t)r;

        unsigned long long ball = __ballot(r == (uint_t)v);
        if (lane == 0) atomicAdd(&ncomp_s, (uint_t)__popcll(ball));
        __syncthreads();   // H
        if (ncomp_s == 1u) break;
    }

#pragma unroll
    for (int m = 32; m >= 1; m >>= 1) acc += __shfl_xor(acc, m, 64);
    if (lane == 0) fsum[wv] = acc;
    __syncthreads();
    if (v == 0) {
        float s = 0.f;
#pragma unroll
        for (int i = 0; i < 16; ++i) s += fsum[i];
        atomicAdd(out, s * scale);
    }
}

// ===================== tier 2: R9 Borůvka (proven @498µs) ===================
__global__ __launch_bounds__(1024)
void boruvka_kernel(const uchar_t* __restrict__ D8, float* __restrict__ out,
                    float scale) {
    const int sl   = blockIdx.x;
    const int v    = threadIdx.x;
    const int lane = v & 63;
    const int wv   = v >> 6;
    const uchar_t* Dbase = D8 + ((size_t)sl << 20);

    __shared__ uint_t   nnlist[NPTS * 8];
    __shared__ ushort_t root16[NPTS];
    __shared__ uint_t   best[NPTS];
    __shared__ ushort_t rq[NPTS];
    __shared__ uint_t   rqn, ncomp_s;
    __shared__ float    fsum[16];

    uint_t slotv[8];
#pragma unroll
    for (int m = 0; m < 8; ++m)
        slotv[m] = ((uint_t)(2 * m + 1) << 16) | (uint_t)(2 * m);

    {
        uint4 rc = ((const uint4*)(Dbase + ((size_t)wv << 10)))[lane];
        for (int i = 0; i < 64; ++i) {
            const int row = wv + 16 * i;
            uint4 rn = rc;
            if (i < 63)
                rn = ((const uint4*)(Dbase + ((size_t)(row + 16) << 10)))[lane];
            uint_t md[8];
            md[0] = __builtin_amdgcn_perm(rc.x, slotv[0], SEL_LO);
            md[1] = __builtin_amdgcn_perm(rc.x, slotv[1], SEL_HI);
            md[2] = __builtin_amdgcn_perm(rc.y, slotv[2], SEL_LO);
            md[3] = __builtin_amdgcn_perm(rc.y, slotv[3], SEL_HI);
            md[4] = __builtin_amdgcn_perm(rc.z, slotv[4], SEL_LO);
            md[5] = __builtin_amdgcn_perm(rc.z, slotv[5], SEL_HI);
            md[6] = __builtin_amdgcn_perm(rc.w, slotv[6], SEL_LO);
            md[7] = __builtin_amdgcn_perm(rc.w, slotv[7], SEL_HI);
            {
                const bool win = (row >> 4) == lane;
                const uint_t s4 = (uint_t)(row & 15);
#pragma unroll
                for (int m = 0; m < 8; ++m) {
                    uint_t h = (win && s4 == 2u * m)      ? 0x0000FFFFu
                             : (win && s4 == 2u * m + 1u) ? 0xFFFF0000u : 0u;
                    md[m] |= h;
                }
            }
#pragma unroll
            for (int k = 0; k < 8; ++k) {
                uint_t t0 = pk_min_u16(pk_min_u16(md[0], md[1]), pk_min_u16(md[2], md[3]));
                uint_t t1 = pk_min_u16(pk_min_u16(md[4], md[5]), pk_min_u16(md[6], md[7]));
                uint_t tt = pk_min_u16(t0, t1);
                uint_t v16 = umin_u(tt & 0xFFFFu, tt >> 16);
                uint_t key = ((v16 & 0xFF00u) << 2) | ((uint_t)lane << 4) | (v16 & 15u);
                DPP_REDUCE(key);
                uint_t g = (uint_t)__builtin_amdgcn_readlane((int)key, 63);
                if (lane == 0) nnlist[row * 8 + k] = g;
                const uint_t wl = (g >> 4) & 63u, ws = g & 15u;
                const bool win = (uint_t)lane == wl;
#pragma unroll
                for (int m = 0; m < 8; ++m) {
                    uint_t h = (win && ws == 2u * m)      ? 0x0000FFFFu
                             : (win && ws == 2u * m + 1u) ? 0xFFFF0000u : 0u;
                    md[m] |= h;
                }
            }
            rc = rn;
        }
    }
    root16[v] = (ushort_t)v;
    __syncthreads();

    uint_t nn[8];
#pragma unroll
    for (int k = 0; k < 8; ++k) nn[k] = nnlist[v * 8 + k];
    const uint_t q8 = nn[7] >> 10;

    float acc = 0.f;
    for (int round = 0; round < 12; ++round) {
        best[v] = 0xFFFFFFFFu;
        if (v == 0) { rqn = 0; ncomp_s = 0; }
        __syncthreads();
        const uint_t rv = root16[v];
        uint_t cand = 0xFFFFFFFFu;
#pragma unroll
        for (int k = 0; k < 8; ++k) {
            uint_t e = nn[k];
            uint_t j = e & 1023u;
            if (root16[j] != (ushort_t)rv) {
                uint_t q = e >> 10;
                uint_t a = umin_u((uint_t)v, j), b = umax_u((uint_t)v, j);
                cand = umin_u(cand, (q << 20) | (a << 10) | b);
            }
        }
        if (cand != 0xFFFFFFFFu) atomicMin(&best[rv], cand);
        if (cand == 0xFFFFFFFFu || (cand >> 20) >= q8) {
            uint_t idx = atomicAdd(&rqn, 1u);
            rq[idx] = (ushort_t)v;
        }
        __syncthreads();
        for (uint_t qi = (uint_t)wv; qi < rqn; qi += 16) {
            const uint_t row = rq[qi];
            const uint_t rr  = root16[row];
            uint4 r = ((const uint4*)(Dbase + ((size_t)row << 10)))[lane];
            uint_t bl = 0xFFFFFFFFu;
            const uint_t base = (uint_t)lane * 16u;
#pragma unroll
            for (int k = 0; k < 16; ++k) {
                uint_t j = base + (uint_t)k;
                uint_t q = (k < 4  ? (r.x >> (8 * k))
                          : k < 8  ? (r.y >> (8 * (k - 4)))
                          : k < 12 ? (r.z >> (8 * (k - 8)))
                                   : (r.w >> (8 * (k - 12)))) & 0xFFu;
                uint_t a = umin_u(row, j), b = umax_u(row, j);
                if (root16[j] != (ushort_t)rr)
                    bl = umin_u(bl, (q << 20) | (a << 10) | b);
            }
            DPP_REDUCE(bl);
            uint_t g = (uint_t)__builtin_amdgcn_readlane((int)bl, 63);
            if (lane == 0 && g != 0xFFFFFFFFu) atomicMin(&best[rr], g);
        }
        __syncthreads();
        const bool isroot = (rv == (uint_t)v);
        bool hook = false;
        uint_t o = (uint_t)v;
        if (isroot) {
            uint_t K = best[v];
            if (K != 0xFFFFFFFFu) {
                uint_t a = (K >> 10) & 1023u, b = K & 1023u, q = K >> 20;
                uint_t ra = root16[a], rb = root16[b];
                o = (ra == (uint_t)v) ? rb : ra;
                bool mutual = (best[o] == K);
                if (!mutual || (uint_t)v > o) {
                    hook = true;
                    acc += sqrtf(2.0f * (float)q);
                }
            }
        }
        __syncthreads();
        if (hook) root16[v] = (ushort_t)o;
        __syncthreads();
        uint_t r = root16[v];
        uint_t pr = root16[r];
        for (int sgs = 0; sgs < 1024 && pr != r; ++sgs) { r = pr; pr = root16[r]; }
        __syncthreads();
        root16[v] = (ushort_t)r;
        unsigned long long ball = __ballot(r == (uint_t)v);
        if (lane == 0) atomicAdd(&ncomp_s, (uint_t)__popcll(ball));
        __syncthreads();
        if (ncomp_s == 1u) break;
    }
#pragma unroll
    for (int m = 32; m >= 1; m >>= 1) acc += __shfl_xor(acc, m, 64);
    if (lane == 0) fsum[wv] = acc;
    __syncthreads();
    if (v == 0) {
        float s = 0.f;
#pragma unroll
        for (int i = 0; i < 16; ++i) s += fsum[i];
        atomicAdd(out, s * scale);
    }
}

// ===================== tier 3: single-wave Prim (R5) ========================
__global__ __launch_bounds__(64, 1)
void prim_u8_kernel(const uchar_t* __restrict__ D8, float* __restrict__ out,
                    float scale) {
    const int sl   = blockIdx.x;
    const int lane = threadIdx.x;
    const uchar_t* Dbase = D8 + ((size_t)sl << 20);

    uint_t md[8], po[8], slotv[8];
#pragma unroll
    for (int m = 0; m < 8; ++m) {
        md[m] = 0xFFFFFFFFu; po[m] = 0u;
        slotv[m] = ((uint_t)(2 * m + 1) << 16) | (uint_t)(2 * m);
    }
    const uint_t lane16 = (uint_t)lane << 4;
    uint_t p   = 0;
    float  acc = 0.f;

    for (int it = 0; it < NPTS - 1; ++it) {
        const uint4* rp = (const uint4*)(Dbase + ((size_t)p << 10));
        uint4 r = rp[lane];
        const bool  win = (p >> 4) == (uint_t)lane;
        const uint_t s4 = p & 15u;
#pragma unroll
        for (int m = 0; m < 8; ++m) {
            uint_t h = (win && s4 == 2u * m)      ? 0x0000FFFFu
                     : (win && s4 == 2u * m + 1u) ? 0xFFFF0000u : 0u;
            md[m] |= h; po[m] |= h;
        }
        md[0] = pk_min_u16(md[0], pk_max_u16(__builtin_amdgcn_perm(r.x, slotv[0], SEL_LO), po[0]));
        md[1] = pk_min_u16(md[1], pk_max_u16(__builtin_amdgcn_perm(r.x, slotv[1], SEL_HI), po[1]));
        md[2] = pk_min_u16(md[2], pk_max_u16(__builtin_amdgcn_perm(r.y, slotv[2], SEL_LO), po[2]));
        md[3] = pk_min_u16(md[3], pk_max_u16(__builtin_amdgcn_perm(r.y, slotv[3], SEL_HI), po[3]));
        md[4] = pk_min_u16(md[4], pk_max_u16(__builtin_amdgcn_perm(r.z, slotv[4], SEL_LO), po[4]));
        md[5] = pk_min_u16(md[5], pk_max_u16(__builtin_amdgcn_perm(r.z, slotv[5], SEL_HI), po[5]));
        md[6] = pk_min_u16(md[6], pk_max_u16(__builtin_amdgcn_perm(r.w, slotv[6], SEL_LO), po[6]));
        md[7] = pk_min_u16(md[7], pk_max_u16(__builtin_amdgcn_perm(r.w, slotv[7], SEL_HI), po[7]));

        uint_t t0 = pk_min_u16(pk_min_u16(md[0], md[1]), pk_min_u16(md[2], md[3]));
        uint_t t1 = pk_min_u16(pk_min_u16(md[4], md[5]), pk_min_u16(md[6], md[7]));
        uint_t tt = pk_min_u16(t0, t1);
        uint_t v16 = umin_u(tt & 0xFFFFu, tt >> 16);

        uint_t key = ((v16 & 0xFF00u) << 2) | lane16 | (v16 & 15u);
        DPP_REDUCE(key);
        uint_t g = (uint_t)__builtin_amdgcn_readlane((int)key, 63);

        p = g & 1023u;
        acc += sqrtf(2.0f * (float)(g >> 10));
    }
    if (lane == 0) atomicAdd(out, acc * scale);
}

// ===================== tier 4 fallback (R3) =================================
#define NTHR 256
#define NWAVE 4
#define PPT  4
__global__ __launch_bounds__(NTHR, 1)
void prim_mst_kernel(const float* __restrict__ reps, float* __restrict__ out,
                     float scale) {
    const int s = blockIdx.x, t = threadIdx.x, lane = t & 63, wave = t >> 6;
    __shared__ uint4  sc[NH2 / 4];
    __shared__ float  snrm;
    __shared__ __align__(16) uint_t warr[NWAVE];
    __shared__ float  facc[NWAVE];
    uint_t cx[PPT][NH2]; float nrm[PPT], mind[PPT];
#pragma unroll
    for (int p = 0; p < PPT; ++p) {
        const float4* src = (const float4*)(reps + (size_t)s * (NPTS * DIM) +
                                            (size_t)(p * NTHR + t) * DIM);
        float n = 0.f;
#pragma unroll
        for (int k = 0; k < 32; ++k) {
            float4 v = src[k];
            h2 a; a[0] = (_Float16)v.x; a[1] = (_Float16)v.y;
            h2 b; b[0] = (_Float16)v.z; b[1] = (_Float16)v.w;
            cx[p][2 * k] = __builtin_bit_cast(uint_t, a);
            cx[p][2 * k + 1] = __builtin_bit_cast(uint_t, b);
            n = dot2f(cx[p][2 * k], cx[p][2 * k], n);
            n = dot2f(cx[p][2 * k + 1], cx[p][2 * k + 1], n);
        }
        nrm[p] = n; mind[p] = 3.0e38f;
    }
    uint_t vis = 0;
    if (t == 0) {
#pragma unroll
        for (int k = 0; k < NH2 / 4; ++k)
            sc[k] = make_uint4(cx[0][4 * k], cx[0][4 * k + 1], cx[0][4 * k + 2], cx[0][4 * k + 3]);
        snrm = nrm[0]; vis = 1;
    }
    __syncthreads();
    float acc = 0.f;
    for (int it = 0; it < NPTS - 1; ++it) {
        const float bn = snrm;
        float e0[PPT], e1[PPT];
#pragma unroll
        for (int p = 0; p < PPT; ++p) { e0[p] = 0.f; e1[p] = 0.f; }
#pragma unroll
        for (int k = 0; k < NH2 / 4; ++k) {
            uint4 q = sc[k];
#pragma unroll
            for (int p = 0; p < PPT; ++p) {
                e0[p] = dot2f(cx[p][4 * k + 0], q.x, e0[p]);
                e1[p] = dot2f(cx[p][4 * k + 1], q.y, e1[p]);
                e0[p] = dot2f(cx[p][4 * k + 2], q.z, e0[p]);
                e1[p] = dot2f(cx[p][4 * k + 3], q.w, e1[p]);
            }
        }
        uint_t key = 0xFFFFFFFFu;
#pragma unroll
        for (int p = 0; p < PPT; ++p) {
            float d2 = fmaxf(bn + nrm[p] - 2.f * (e0[p] + e1[p]), 0.f);
            mind[p] = fminf(mind[p], d2);
            uint_t kp = ((vis >> p) & 1u) ? 0xFFFFFFFFu
                      : ((__float_as_uint(mind[p]) & 0xFFFFFC00u) | (uint_t)(p * NTHR + t));
            key = umin_u(key, kp);
        }
        DPP_REDUCE(key);
        uint_t wkey = (uint_t)__builtin_amdgcn_readlane((int)key, 63);
        if (lane == 0) warr[wave] = wkey;
        __syncthreads();
        uint4 wv = *(const uint4*)warr;
        uint_t g = umin_u(umin_u(wv.x, wv.y), umin_u(wv.z, wv.w));
        const int j = (int)(g & 0x3FFu), jp = j >> 8;
        if ((j & (NTHR - 1)) == t) {
#pragma unroll
            for (int p = 0; p < PPT; ++p)
                if (jp == p) {
#pragma unroll
                    for (int k = 0; k < NH2 / 4; ++k)
                        sc[k] = make_uint4(cx[p][4 * k], cx[p][4 * k + 1],
                                           cx[p][4 * k + 2], cx[p][4 * k + 3]);
                    snrm = nrm[p]; acc += sqrtf(mind[p]);
                }
            vis |= 1u << jp;
        }
        __syncthreads();
    }
#pragma unroll
    for (int m = 32; m >= 1; m >>= 1) acc += __shfl_xor(acc, m, 64);
    if (lane == 0) facc[wave] = acc;
    __syncthreads();
    if (t == 0) atomicAdd(out, (facc[0] + facc[1] + facc[2] + facc[3]) * scale);
}

// ============================ launch ========================================
extern "C" void kernel_launch(void* const* d_in, const int* in_sizes, int n_in,
                              void* d_out, int out_size, void* d_ws, size_t ws_size,
                              hipStream_t stream) {
    const float* reps = (const float*)d_in[0];
    float*       out  = (float*)d_out;
    const int ns = in_sizes[0] / (NPTS * DIM);
    const float scale = 1.0f / ((float)(NPTS - 1) * (float)ns * 2.0f);

    hipMemsetAsync(out, 0, sizeof(float), stream);

    const size_t bytes_D  = (size_t)ns << 20;
    const size_t bytes_P  = (size_t)ns << 18;
    const size_t bytes_NN = (size_t)ns << 14;   // 1024 rows * 4 * 4B
    const size_t bytes_N  = (size_t)ns << 12;

    if (ws_size >= bytes_D + bytes_P + bytes_NN + bytes_N) {
        // tier 1: prep -> 64-row-strip gram+NN4 fused -> Borůvka v4
        uchar_t*  D8    = (uchar_t*)d_ws;
        ushort_t* P16   = (ushort_t*)((char*)d_ws + bytes_D);
        uint_t*   NN4   = (uint_t*)((char*)d_ws + bytes_D + bytes_P);
        float*    norms = (float*)((char*)d_ws + bytes_D + bytes_P + bytes_NN);
        const int xcd_affine = ((ns & 7) == 0) ? 1 : 0;
        prep_kernel<<<dim3(ns * 64), dim3(256), 0, stream>>>(reps, P16, norms);
        gram16f_kernel<<<dim3(ns * 16), dim3(256), 0, stream>>>(P16, norms, D8, NN4,
                                                                xcd_affine);
        boruvka4_kernel<<<dim3(ns), dim3(1024), 0, stream>>>(D8, NN4, out, scale);
    } else if (ws_size >= bytes_D + bytes_N) {
        // tier 2: exact R9 path (proven 498 µs)
        uchar_t* D8    = (uchar_t*)d_ws;
        float*   norms = (float*)((char*)d_ws + bytes_D);
        norms_kernel<<<dim3(ns * 64), dim3(256), 0, stream>>>(reps, norms);
        gram_kernel<<<dim3(ns * 64), dim3(256), 0, stream>>>(reps, norms, D8, 0);
        boruvka_kernel<<<dim3(ns), dim3(1024), 0, stream>>>(D8, out, scale);
    } else {
        int nc = 0;
        size_t norms_off = 0;
        if (ws_size > bytes_N + (1u << 20)) {
            norms_off = (ws_size - bytes_N) & ~(size_t)15;
            nc = (int)(norms_off >> 20);
            if (nc > ns) nc = ns;
        }
        if (nc >= 32) {
            uchar_t* D8    = (uchar_t*)d_ws;
            float*   norms = (float*)((char*)d_ws + norms_off);
            norms_kernel<<<dim3(ns * 64), dim3(256), 0, stream>>>(reps, norms);
            for (int base = 0; base < ns; base += nc) {
                const int n = (ns - base < nc) ? (ns - base) : nc;
                gram_kernel<<<dim3(n * 64), dim3(256), 0, stream>>>(reps, norms, D8, base);
                prim_u8_kernel<<<dim3(n), dim3(64), 0, stream>>>(D8, out, scale);
            }
        } else {
            prim_mst_kernel<<<dim3(ns), dim3(NTHR), 0, stream>>>(reps, out, scale);
        }
    }
}